// Round 2
// baseline (6363.049 us; speedup 1.0000x reference)
//
#include <hip/hip_runtime.h>
#include <stdint.h>

#define LANE ((int)(threadIdx.x & 63))
#define WID  ((int)(threadIdx.x >> 6))

__device__ __forceinline__ float exact_d2(float ax, float ay, float az,
                                          float bx, float by, float bz) {
  float dx = ax - bx, dy = ay - by, dz = az - bz;
  return __fadd_rn(__fadd_rn(__fmul_rn(dx, dx), __fmul_rn(dy, dy)), __fmul_rn(dz, dz));
}

__device__ __forceinline__ uint64_t shfl_xor_u64(uint64_t v, int off) {
  uint32_t lo = (uint32_t)v, hi = (uint32_t)(v >> 32);
  lo = __shfl_xor(lo, off);
  hi = __shfl_xor(hi, off);
  return ((uint64_t)hi << 32) | lo;
}

__device__ __forceinline__ void lds_fence() {
  asm volatile("s_waitcnt lgkmcnt(0)" ::: "memory");
}

// ---------------- FPS body: one block per batch, 1 barrier/iter, no VMEM in loop ----
// Protocol per iter s: update dd with dist to prev winner (coords carried in regs) ->
// u64 key butterfly -> wave-winner LANE writes (key,xyz) to parity slot s&1 (PRE-barrier)
// -> barrier -> all threads pick max of 4 wave keys, read winner coords (broadcast).
// Global winner thread records sidx/spos (read only after final barrier). Parity
// double-buffering makes the single barrier sufficient (max skew = 1 iteration).
template <int NPTS, int NSAMP>
__device__ void fps_body(const float* __restrict__ coords, int b,
                         int* __restrict__ out_idx, float* __restrict__ out_pos,
                         char* smem_raw) {
  constexpr int PT = NPTS / 256;
  uint64_t* swk = (uint64_t*)smem_raw;                    // [2][4] keys
  float* swc = (float*)(swk + 8);                         // [2][4][4] coords
  float* spos = swc + 32;                                 // [NSAMP*3]
  unsigned short* sidx = (unsigned short*)(spos + NSAMP * 3);  // [NSAMP]
  const float* pos = coords + (size_t)b * NPTS * 3;
  const int tid = (int)threadIdx.x;

  __builtin_amdgcn_s_setprio(3);  // win issue arbitration vs co-resident conv waves

  float px[PT], py[PT], pz[PT], dd[PT];
  const int i0 = tid * PT;
#pragma unroll
  for (int k = 0; k < PT; ++k) {
    px[k] = pos[(i0 + k) * 3 + 0];
    py[k] = pos[(i0 + k) * 3 + 1];
    pz[k] = pos[(i0 + k) * 3 + 2];
    dd[k] = __builtin_inff();
  }
  // carried previous-winner coords; iteration 1 uses point 0
  float fx = pos[0], fy = pos[1], fz = pos[2];
  if (tid == 0) {
    sidx[0] = 0;
    spos[0] = fx; spos[1] = fy; spos[2] = fz;
  }
  __syncthreads();

  for (int s = 1; s < NSAMP; ++s) {
    uint64_t myk = 0;
    int bestk = 0;
#pragma unroll
    for (int k = 0; k < PT; ++k) {
      float d = exact_d2(px[k], py[k], pz[k], fx, fy, fz);
      dd[k] = fminf(dd[k], d);
      uint64_t key =
          ((uint64_t)__float_as_uint(dd[k]) << 32) | (unsigned)(NPTS - 1 - (i0 + k));
      if (key > myk) { myk = key; bestk = k; }
    }
    uint64_t wk = myk;
#pragma unroll
    for (int off = 1; off < 64; off <<= 1) {
      uint64_t o = shfl_xor_u64(wk, off);
      wk = o > wk ? o : wk;
    }
    const int par = s & 1;
    if (myk == wk) {  // unique wave-winner lane: publish key + coords pre-barrier
      swk[par * 4 + WID] = wk;
      float* c = swc + (par * 4 + WID) * 4;
      c[0] = px[bestk]; c[1] = py[bestk]; c[2] = pz[bestk];
    }
    __syncthreads();
    uint64_t k0 = swk[par * 4 + 0], k1 = swk[par * 4 + 1];
    uint64_t k2 = swk[par * 4 + 2], k3 = swk[par * 4 + 3];
    uint64_t kk = k0; int w = 0;
    if (k1 > kk) { kk = k1; w = 1; }
    if (k2 > kk) { kk = k2; w = 2; }
    if (k3 > kk) { kk = k3; w = 3; }
    const float* c = swc + (par * 4 + w) * 4;
    fx = c[0]; fy = c[1]; fz = c[2];
    if (myk == kk) {  // unique global winner records outputs (read after final barrier)
      sidx[s] = (unsigned short)(i0 + bestk);
      spos[s * 3 + 0] = px[bestk];
      spos[s * 3 + 1] = py[bestk];
      spos[s * 3 + 2] = pz[bestk];
    }
  }
  __syncthreads();
  for (int s = tid; s < NSAMP; s += 256) {
    out_idx[(size_t)b * NSAMP + s] = (int)sidx[s];
    if (out_pos) {
      out_pos[((size_t)b * NSAMP + s) * 3 + 0] = spos[s * 3 + 0];
      out_pos[((size_t)b * NSAMP + s) * 3 + 1] = spos[s * 3 + 1];
      out_pos[((size_t)b * NSAMP + s) * 3 + 2] = spos[s * 3 + 2];
    }
  }
}

// ---------------- PointConv body: 1 wave per query ----------------
// Exact neighbor set = in-radius candidates, restricted to the 64 nearest (d, then j)
// when count > 64 -- found by binary search on distance bits with ballot counting,
// exact tie resolution on j. Layer1 factored: y1 = relu(b1 + x@W1f + rel@W1r).
// Layer2: per-g SGPR weight rows, LDS [32][65] transpose stage for the lane-max.
template <int NPTS, int H, int CAP, bool PRECOMP>
__device__ void conv_body(const float* __restrict__ pos, const float* __restrict__ xsrc,
                          const float* __restrict__ w1f, const float* __restrict__ b1,
                          const float* __restrict__ w1r, const float* __restrict__ w2t,
                          const float* __restrict__ b2, float r2,
                          float* __restrict__ out, int qid, char* wmem) {
  constexpr int SLOTS = CAP / 64;
  const int lane = LANE;
  const int b = qid / NPTS, qi = qid % NPTS;
  const float* bpos = pos + (size_t)b * NPTS * 3;
  const float qx = bpos[qi * 3 + 0], qy = bpos[qi * 3 + 1], qz = bpos[qi * 3 + 2];
  uint64_t* list = (uint64_t*)wmem;
  const uint64_t ltmask = (1ull << lane) - 1ull;

  // ---- scan: compact in-radius candidates (d < r2, matching jax f32 compare) ----
  unsigned cnt = 0;
  for (int base = 0; base < NPTS; base += 64) {
    int j = base + lane;
    float d = exact_d2(bpos[j * 3], bpos[j * 3 + 1], bpos[j * 3 + 2], qx, qy, qz);
    bool pred = d < r2;
    uint64_t mask = __ballot(pred);
    if (pred) {
      unsigned p = cnt + (unsigned)__popcll(mask & ltmask);
      if (p < CAP) list[p] = ((uint64_t)__float_as_uint(d) << 32) | (unsigned)j;
    }
    cnt += (unsigned)__popcll(mask);
  }
  if (cnt > CAP) cnt = CAP;
  lds_fence();

  // ---- exact selection of min(cnt,64) neighbors ----
  int m;
  unsigned nbr = 0;
  if (cnt <= 64) {
    m = (int)cnt;
    if (lane < m) nbr = (unsigned)list[lane];
  } else {
    m = 64;
    uint64_t e[SLOTS];
#pragma unroll
    for (int si = 0; si < SLOTS; ++si) {
      int p = lane + 64 * si;
      e[si] = (p < (int)cnt) ? list[p] : ~0ull;
    }
    // binary search for d* = 64th smallest distance (bit pattern, all d in [0,1))
    unsigned lo = 0, hi = 0x3F800000u;
    while (lo < hi) {
      unsigned mid = (lo + hi) >> 1;
      unsigned c = 0;
#pragma unroll
      for (int si = 0; si < SLOTS; ++si)
        c += (unsigned)__popcll(__ballot((unsigned)(e[si] >> 32) <= mid));
      if (c >= 64u) hi = mid; else lo = mid + 1;
    }
    const unsigned dstar = lo;
    unsigned nlt = 0, nt = 0;
#pragma unroll
    for (int si = 0; si < SLOTS; ++si) {
      unsigned hb = (unsigned)(e[si] >> 32);
      nlt += (unsigned)__popcll(__ballot(hb < dstar));
      nt += (unsigned)__popcll(__ballot(hb == dstar));
    }
    const unsigned need = 64u - nlt;
    unsigned jsel = 0xFFFFFFFFu;
    if (nt != need) {  // rare: distance tie at the cut -> keep `need` smallest j
      unsigned jlo = 0, jhi = (unsigned)NPTS - 1;
      while (jlo < jhi) {
        unsigned jmid = (jlo + jhi) >> 1;
        unsigned c = 0;
#pragma unroll
        for (int si = 0; si < SLOTS; ++si)
          c += (unsigned)__popcll(__ballot(
              ((unsigned)(e[si] >> 32) == dstar) && ((unsigned)e[si] <= jmid)));
        if (c >= need) jhi = jmid; else jlo = jmid + 1;
      }
      jsel = jlo;
    }
    // compact exactly 64 winners into LDS, one per lane
    unsigned c2 = 0;
    unsigned* jl = (unsigned*)wmem;
#pragma unroll
    for (int si = 0; si < SLOTS; ++si) {
      unsigned hb = (unsigned)(e[si] >> 32), jj = (unsigned)e[si];
      bool p = (hb < dstar) || ((hb == dstar) && (jj <= jsel));
      uint64_t mask = __ballot(p);
      if (p) jl[c2 + (unsigned)__popcll(mask & ltmask)] = jj;
      c2 += (unsigned)__popcll(mask);
    }
    lds_fence();
    nbr = jl[lane];
  }

  // ---- MLP layer 1 (per-lane neighbor), bitwise-identical fmaf order to R0 ----
  const bool valid = lane < m;
  const int j = valid ? (int)nbr : 0;
  const float rx = bpos[j * 3 + 0] - qx;
  const float ry = bpos[j * 3 + 1] - qy;
  const float rz = bpos[j * 3 + 2] - qz;

  float y1[H];
  if constexpr (!PRECOMP) {
    const float* xr = xsrc + ((size_t)b * NPTS + j) * 6;
    float x0 = xr[0], x1 = xr[1], x2 = xr[2], x3 = xr[3], x4 = xr[4], x5 = xr[5];
#pragma unroll
    for (int f = 0; f < H; ++f) {
      float a = b1[f];
      a = fmaf(x0, w1f[0 * H + f], a);
      a = fmaf(x1, w1f[1 * H + f], a);
      a = fmaf(x2, w1f[2 * H + f], a);
      a = fmaf(x3, w1f[3 * H + f], a);
      a = fmaf(x4, w1f[4 * H + f], a);
      a = fmaf(x5, w1f[5 * H + f], a);
      y1[f] = a;
    }
  } else {
    const float* urow = xsrc + ((size_t)b * NPTS + j) * H;
#pragma unroll
    for (int f = 0; f < H; f += 4) {
      float4 v = *reinterpret_cast<const float4*>(urow + f);
      y1[f] = v.x; y1[f + 1] = v.y; y1[f + 2] = v.z; y1[f + 3] = v.w;
    }
  }
#pragma unroll
  for (int f = 0; f < H; ++f) {
    float t0 = fmaf(rx, w1r[f], y1[f]);
    t0 = fmaf(ry, w1r[H + f], t0);
    t0 = fmaf(rz, w1r[2 * H + f], t0);
    y1[f] = fmaxf(t0, 0.0f);
  }

  // ---- layer 2 + max aggregation via LDS transpose stage ----
  float* stg = (float*)wmem;  // [32][65] floats, reuses candidate area
  float* orow = out + (size_t)qid * H;
  const float NEG = -__builtin_inff();
#pragma unroll 1
  for (int cst = 0; cst < H; cst += 32) {
    lds_fence();  // prior-chunk reads (and jl read) complete before overwrite
#pragma unroll 2
    for (int g = 0; g < 32; ++g) {
      const float* wrow = w2t + (size_t)(cst + g) * H;  // uniform -> SGPR loads
      float a0 = 0.f, a1 = 0.f, a2 = 0.f, a3 = 0.f;
#pragma unroll
      for (int f = 0; f < H; f += 4) {
        a0 = fmaf(y1[f], wrow[f], a0);
        a1 = fmaf(y1[f + 1], wrow[f + 1], a1);
        a2 = fmaf(y1[f + 2], wrow[f + 2], a2);
        a3 = fmaf(y1[f + 3], wrow[f + 3], a3);
      }
      float acc = b2[cst + g] + ((a0 + a1) + (a2 + a3));
      stg[g * 65 + lane] = valid ? acc : NEG;
    }
    lds_fence();
    const int r = lane & 31, jb = lane & 32;
    float mx = NEG;
#pragma unroll
    for (int t = 0; t < 32; ++t) mx = fmaxf(mx, stg[r * 65 + jb + t]);
    mx = fmaxf(mx, __shfl_xor(mx, 32));
    if (lane < 32) orow[cst + lane] = mx;
  }
}

// ---------------- fused stage kernel: blocks 0..7 = FPS, rest = conv ----------------
template <int NPTS, int NSAMP, int H, int CAP, bool PRECOMP>
__global__ __launch_bounds__(256, 2) void stage_kernel(
    const float* __restrict__ coords, const float* __restrict__ xsrc,
    const float* __restrict__ w1f, const float* __restrict__ b1,
    const float* __restrict__ w1r, const float* __restrict__ w2t,
    const float* __restrict__ b2, float r2, float* __restrict__ out,
    int* __restrict__ fps_idx, float* __restrict__ fps_pos) {
  __shared__ __align__(16) char smem[33280];  // max(fps: <29KB, conv: 4*8320)
  if (blockIdx.x < 8) {
    fps_body<NPTS, NSAMP>(coords, (int)blockIdx.x, fps_idx, fps_pos, smem);
  } else {
    conv_body<NPTS, H, CAP, PRECOMP>(coords, xsrc, w1f, b1, w1r, w2t, b2, r2, out,
                                     ((int)blockIdx.x - 8) * 4 + WID,
                                     smem + WID * 8320);
  }
}

// ------- u2 = b1b + h1[i1] @ W1b_feat (layer-1 factoring for stage 2) -------
__global__ __launch_bounds__(128) void u2_kernel(const float* __restrict__ h1,
                                                 const int* __restrict__ i1,
                                                 const float* __restrict__ w1,
                                                 const float* __restrict__ b1,
                                                 float* __restrict__ u2) {
  int row = blockIdx.x;  // 16384
  int f = (int)threadIdx.x;
  int b = row >> 11;
  int src = i1[row];
  const float* x = h1 + ((size_t)b * 4096 + src) * 64;
  float acc = b1[f];
#pragma unroll
  for (int k = 0; k < 64; ++k) acc = fmaf(x[k], w1[k * 128 + f], acc);
  u2[(size_t)row * 128 + f] = acc;
}

__global__ __launch_bounds__(256) void transpose_kernel(const float* __restrict__ w2a,
                                                        const float* __restrict__ w2b,
                                                        float* __restrict__ w2ta,
                                                        float* __restrict__ w2tb) {
  int gtid = blockIdx.x * 256 + (int)threadIdx.x;
  int stride = gridDim.x * 256;
  for (int t = gtid; t < 64 * 64; t += stride) w2ta[(t & 63) * 64 + (t >> 6)] = w2a[t];
  for (int t = gtid; t < 128 * 128; t += stride) w2tb[(t & 127) * 128 + (t >> 7)] = w2b[t];
}

// ---------------- global max pool over i2 + final linear ----------------
__global__ __launch_bounds__(512) void pool_linear_kernel(
    const float* __restrict__ h2, const int* __restrict__ i2,
    const float* __restrict__ wl, const float* __restrict__ bl,
    float* __restrict__ out) {
  int b = blockIdx.x;
  int c = (int)threadIdx.x >> 7;
  int f = (int)threadIdx.x & 127;
  __shared__ float part[4][128];
  __shared__ float feat[128];
  float mx = -__builtin_inff();
  const int* idx = i2 + b * 512;
  for (int s = c * 128; s < c * 128 + 128; ++s) {
    int j = idx[s];
    mx = fmaxf(mx, h2[((size_t)b * 2048 + j) * 128 + f]);
  }
  part[c][f] = mx;
  __syncthreads();
  if (c == 0) {
    feat[f] = fmaxf(fmaxf(part[0][f], part[1][f]), fmaxf(part[2][f], part[3][f]));
  }
  __syncthreads();
  if (c == 0) {
    float acc = bl[f];
#pragma unroll
    for (int k = 0; k < 128; ++k) acc = fmaf(feat[k], wl[k * 128 + f], acc);
    out[b * 128 + f] = acc;
  }
}

extern "C" void kernel_launch(void* const* d_in, const int* in_sizes, int n_in,
                              void* d_out, int out_size, void* d_ws, size_t ws_size,
                              hipStream_t stream) {
  const float* feats = (const float*)d_in[0];   // [8,4096,6]
  const float* coords = (const float*)d_in[1];  // [8,4096,3]
  const float* W1a = (const float*)d_in[2];     // [9,64]
  const float* b1a = (const float*)d_in[3];
  const float* W2a = (const float*)d_in[4];     // [64,64]
  const float* b2a = (const float*)d_in[5];
  const float* W1b = (const float*)d_in[6];     // [67,128]
  const float* b1b = (const float*)d_in[7];
  const float* W2b = (const float*)d_in[8];     // [128,128]
  const float* b2b = (const float*)d_in[9];
  const float* Wl = (const float*)d_in[10];     // [128,128]
  const float* bl = (const float*)d_in[11];

  float* ws = (float*)d_ws;
  float* W2TA = ws;                  // 4096
  float* W2TB = W2TA + 4096;         // 16384
  float* H1 = W2TB + 16384;          // 8*4096*64  = 2097152
  float* U2 = H1 + 2097152;          // 8*2048*128 = 2097152
  float* H2 = U2 + 2097152;          // 8*2048*128 = 2097152
  float* P1 = H2 + 2097152;          // 8*2048*3   = 49152
  int* I1 = (int*)(P1 + 49152);      // 8*2048
  int* I2 = I1 + 16384;              // 8*512

  transpose_kernel<<<80, 256, 0, stream>>>(W2a, W2b, W2TA, W2TB);
  // stage 1: fps1 (blocks 0-7) || conv1 (8192 blocks, layer-1 inlined from feats)
  stage_kernel<4096, 2048, 64, 512, false><<<8 + 8192, 256, 0, stream>>>(
      coords, feats, W1a, b1a, W1a + 6 * 64, W2TA, b2a, 0.04f, H1, I1, P1);
  u2_kernel<<<16384, 128, 0, stream>>>(H1, I1, W1b, b1b, U2);
  // stage 2: fps2 (blocks 0-7) || conv2 (4096 blocks, precomputed U2)
  stage_kernel<2048, 512, 128, 1024, true><<<8 + 4096, 256, 0, stream>>>(
      P1, U2, nullptr, nullptr, W1b + 64 * 128, W2TB, b2b, 0.16f, H2, I2, nullptr);
  pool_linear_kernel<<<8, 512, 0, stream>>>(H2, I2, Wl, bl, (float*)d_out);
}

// Round 3
// 6155.354 us; speedup vs baseline: 1.0337x; 1.0337x over previous
//
#include <hip/hip_runtime.h>
#include <stdint.h>

#define LANE ((int)(threadIdx.x & 63))
#define WID  ((int)(threadIdx.x >> 6))

__device__ __forceinline__ float exact_d2(float ax, float ay, float az,
                                          float bx, float by, float bz) {
  float dx = ax - bx, dy = ay - by, dz = az - bz;
  return __fadd_rn(__fadd_rn(__fmul_rn(dx, dx), __fmul_rn(dy, dy)), __fmul_rn(dz, dz));
}

__device__ __forceinline__ uint64_t shfl_xor_u64(uint64_t v, int off) {
  uint32_t lo = (uint32_t)v, hi = (uint32_t)(v >> 32);
  lo = __shfl_xor(lo, off);
  hi = __shfl_xor(hi, off);
  return ((uint64_t)hi << 32) | lo;
}

__device__ __forceinline__ void lds_fence() {
  asm volatile("s_waitcnt lgkmcnt(0)" ::: "memory");
}

// ---------------- FPS body: one block per batch, 1 barrier/iter, no VMEM in loop ----
template <int NPTS, int NSAMP>
__device__ void fps_body(const float* __restrict__ coords, int b,
                         int* __restrict__ out_idx, float* __restrict__ out_pos,
                         char* smem_raw) {
  constexpr int PT = NPTS / 256;
  uint64_t* swk = (uint64_t*)smem_raw;                         // [2][4] keys
  float* swc = (float*)(swk + 8);                              // [2][4][4] coords
  float* spos = swc + 32;                                      // [NSAMP*3]
  unsigned short* sidx = (unsigned short*)(spos + NSAMP * 3);  // [NSAMP]
  const float* pos = coords + (size_t)b * NPTS * 3;
  const int tid = (int)threadIdx.x;

  __builtin_amdgcn_s_setprio(1);  // FPS is the serial critical path

  float px[PT], py[PT], pz[PT], dd[PT];
  const int i0 = tid * PT;
#pragma unroll
  for (int k = 0; k < PT; ++k) {
    px[k] = pos[(i0 + k) * 3 + 0];
    py[k] = pos[(i0 + k) * 3 + 1];
    pz[k] = pos[(i0 + k) * 3 + 2];
    dd[k] = __builtin_inff();
  }
  float fx = pos[0], fy = pos[1], fz = pos[2];
  if (tid == 0) {
    sidx[0] = 0;
    spos[0] = fx; spos[1] = fy; spos[2] = fz;
  }
  __syncthreads();

  for (int s = 1; s < NSAMP; ++s) {
    uint64_t myk = 0;
    int bestk = 0;
#pragma unroll
    for (int k = 0; k < PT; ++k) {
      float d = exact_d2(px[k], py[k], pz[k], fx, fy, fz);
      dd[k] = fminf(dd[k], d);
      uint64_t key =
          ((uint64_t)__float_as_uint(dd[k]) << 32) | (unsigned)(NPTS - 1 - (i0 + k));
      if (key > myk) { myk = key; bestk = k; }
    }
    uint64_t wk = myk;
#pragma unroll
    for (int off = 1; off < 64; off <<= 1) {
      uint64_t o = shfl_xor_u64(wk, off);
      wk = o > wk ? o : wk;
    }
    const int par = s & 1;
    if (myk == wk) {  // unique wave-winner lane publishes key+coords pre-barrier
      swk[par * 4 + WID] = wk;
      float* c = swc + (par * 4 + WID) * 4;
      c[0] = px[bestk]; c[1] = py[bestk]; c[2] = pz[bestk];
    }
    __syncthreads();
    uint64_t k0 = swk[par * 4 + 0], k1 = swk[par * 4 + 1];
    uint64_t k2 = swk[par * 4 + 2], k3 = swk[par * 4 + 3];
    uint64_t kk = k0; int w = 0;
    if (k1 > kk) { kk = k1; w = 1; }
    if (k2 > kk) { kk = k2; w = 2; }
    if (k3 > kk) { kk = k3; w = 3; }
    const float* c = swc + (par * 4 + w) * 4;
    fx = c[0]; fy = c[1]; fz = c[2];
    if (myk == kk) {  // unique global winner records outputs
      sidx[s] = (unsigned short)(i0 + bestk);
      spos[s * 3 + 0] = px[bestk];
      spos[s * 3 + 1] = py[bestk];
      spos[s * 3 + 2] = pz[bestk];
    }
  }
  __syncthreads();
  for (int s = tid; s < NSAMP; s += 256) {
    out_idx[(size_t)b * NSAMP + s] = (int)sidx[s];
    if (out_pos) {
      out_pos[((size_t)b * NSAMP + s) * 3 + 0] = spos[s * 3 + 0];
      out_pos[((size_t)b * NSAMP + s) * 3 + 1] = spos[s * 3 + 1];
      out_pos[((size_t)b * NSAMP + s) * 3 + 2] = spos[s * 3 + 2];
    }
  }
}

// ---- exact neighbor selection: in-radius candidates, 64 nearest (d, then j) ----
// Fills jl[0..63] (zeros beyond m). e[] registers live only inside this function.
template <int NPTS, int CAP>
__device__ __forceinline__ int select_neighbors(const float* __restrict__ bpos,
                                                float qx, float qy, float qz, float r2,
                                                char* wmem, unsigned* jl) {
  constexpr int SLOTS = CAP / 64;
  const int lane = LANE;
  uint64_t* list = (uint64_t*)wmem;
  const uint64_t ltmask = (1ull << lane) - 1ull;

  unsigned cnt = 0;
  for (int base = 0; base < NPTS; base += 64) {
    int j = base + lane;
    float d = exact_d2(bpos[j * 3], bpos[j * 3 + 1], bpos[j * 3 + 2], qx, qy, qz);
    bool pred = d < r2;
    uint64_t mask = __ballot(pred);
    if (pred) {
      unsigned p = cnt + (unsigned)__popcll(mask & ltmask);
      if (p < CAP) list[p] = ((uint64_t)__float_as_uint(d) << 32) | (unsigned)j;
    }
    cnt += (unsigned)__popcll(mask);
  }
  if (cnt > CAP) cnt = CAP;
  lds_fence();

  int m;
  if (cnt <= 64) {
    m = (int)cnt;
    jl[lane] = (lane < m) ? (unsigned)list[lane] : 0u;
  } else {
    m = 64;
    uint64_t e[SLOTS];
#pragma unroll
    for (int si = 0; si < SLOTS; ++si) {
      int p = lane + 64 * si;
      e[si] = (p < (int)cnt) ? list[p] : ~0ull;
    }
    // binary search for d* = 64th smallest distance bit-pattern
    unsigned lo = 0, hi = 0x3F800000u;
    while (lo < hi) {
      unsigned mid = (lo + hi) >> 1;
      unsigned c = 0;
#pragma unroll
      for (int si = 0; si < SLOTS; ++si)
        c += (unsigned)__popcll(__ballot((unsigned)(e[si] >> 32) <= mid));
      if (c >= 64u) hi = mid; else lo = mid + 1;
    }
    const unsigned dstar = lo;
    unsigned nlt = 0, nt = 0;
#pragma unroll
    for (int si = 0; si < SLOTS; ++si) {
      unsigned hb = (unsigned)(e[si] >> 32);
      nlt += (unsigned)__popcll(__ballot(hb < dstar));
      nt += (unsigned)__popcll(__ballot(hb == dstar));
    }
    const unsigned need = 64u - nlt;
    unsigned jsel = 0xFFFFFFFFu;
    if (nt != need) {  // distance tie at the cut -> keep `need` smallest j
      unsigned jlo = 0, jhi = (unsigned)NPTS - 1;
      while (jlo < jhi) {
        unsigned jmid = (jlo + jhi) >> 1;
        unsigned c = 0;
#pragma unroll
        for (int si = 0; si < SLOTS; ++si)
          c += (unsigned)__popcll(__ballot(
              ((unsigned)(e[si] >> 32) == dstar) && ((unsigned)e[si] <= jmid)));
        if (c >= need) jhi = jmid; else jlo = jmid + 1;
      }
      jsel = jlo;
    }
    unsigned c2 = 0;
#pragma unroll
    for (int si = 0; si < SLOTS; ++si) {
      unsigned hb = (unsigned)(e[si] >> 32), jj = (unsigned)e[si];
      bool p = (hb < dstar) || ((hb == dstar) && (jj <= jsel));
      uint64_t mask = __ballot(p);
      if (p) jl[c2 + (unsigned)__popcll(mask & ltmask)] = jj;
      c2 += (unsigned)__popcll(mask);
    }
  }
  lds_fence();
  return m;
}

// ---------------- conv1: H=64, lane = neighbor, y1[64] in regs ----------------
__device__ void conv1_body(const float* __restrict__ pos, const float* __restrict__ feats,
                           const float* __restrict__ w1, const float* __restrict__ b1,
                           const float* __restrict__ w2t, const float* __restrict__ b2,
                           float* __restrict__ out, int qid, char* wmem) {
  const int lane = LANE;
  const int b = qid >> 12, qi = qid & 4095;
  const float* bpos = pos + (size_t)b * 4096 * 3;
  const float qx = bpos[qi * 3 + 0], qy = bpos[qi * 3 + 1], qz = bpos[qi * 3 + 2];
  unsigned* jl = (unsigned*)(wmem + 8320);
  const int m = select_neighbors<4096, 512>(bpos, qx, qy, qz, 0.04f, wmem, jl);

  const bool valid = lane < m;
  const int j = valid ? (int)jl[lane] : 0;
  const float rx = bpos[j * 3 + 0] - qx;
  const float ry = bpos[j * 3 + 1] - qy;
  const float rz = bpos[j * 3 + 2] - qz;
  const float* xr = feats + ((size_t)b * 4096 + j) * 6;
  const float x0 = xr[0], x1 = xr[1], x2 = xr[2], x3 = xr[3], x4 = xr[4], x5 = xr[5];
  const float* w1r = w1 + 6 * 64;

  float y1[64];
#pragma unroll
  for (int f = 0; f < 64; ++f) {
    float a = b1[f];
    a = fmaf(x0, w1[0 * 64 + f], a);
    a = fmaf(x1, w1[1 * 64 + f], a);
    a = fmaf(x2, w1[2 * 64 + f], a);
    a = fmaf(x3, w1[3 * 64 + f], a);
    a = fmaf(x4, w1[4 * 64 + f], a);
    a = fmaf(x5, w1[5 * 64 + f], a);
    a = fmaf(rx, w1r[0 * 64 + f], a);
    a = fmaf(ry, w1r[1 * 64 + f], a);
    a = fmaf(rz, w1r[2 * 64 + f], a);
    y1[f] = fmaxf(a, 0.0f);
  }

  float* stg = (float*)wmem;  // [32][65], reuses candidate area
  float* orow = out + (size_t)qid * 64;
  const float NEG = -__builtin_inff();
#pragma unroll 1
  for (int cst = 0; cst < 64; cst += 32) {
    lds_fence();
#pragma unroll 1
    for (int g = 0; g < 32; ++g) {
      const float* wrow = w2t + (size_t)(cst + g) * 64;  // uniform -> SGPR loads
      float a0 = 0.f, a1 = 0.f, a2 = 0.f, a3 = 0.f;
#pragma unroll
      for (int f = 0; f < 64; f += 4) {
        a0 = fmaf(y1[f], wrow[f], a0);
        a1 = fmaf(y1[f + 1], wrow[f + 1], a1);
        a2 = fmaf(y1[f + 2], wrow[f + 2], a2);
        a3 = fmaf(y1[f + 3], wrow[f + 3], a3);
      }
      float acc = b2[cst + g] + ((a0 + a1) + (a2 + a3));
      stg[g * 65 + lane] = valid ? acc : NEG;
    }
    lds_fence();
    const int r = lane & 31, jb = lane & 32;
    float mx = NEG;
#pragma unroll
    for (int t = 0; t < 32; ++t) mx = fmaxf(mx, stg[r * 65 + jb + t]);
    mx = fmaxf(mx, __shfl_xor(mx, 32));
    if (lane < 32) orow[cst + lane] = mx;
  }
}

// ------- conv2: H=128, lane-pair split (lane 2n: f 0..63, lane 2n+1: f 64..127) -------
__device__ void conv2_body(const float* __restrict__ pos, const float* __restrict__ u,
                           const float* __restrict__ w1r, const float* __restrict__ w2t,
                           const float* __restrict__ b2, float* __restrict__ out,
                           int qid, char* wmem) {
  const int lane = LANE;
  const int b = qid >> 11, qi = qid & 2047;
  const float* bpos = pos + (size_t)b * 2048 * 3;
  const float qx = bpos[qi * 3 + 0], qy = bpos[qi * 3 + 1], qz = bpos[qi * 3 + 2];
  unsigned* jl = (unsigned*)(wmem + 8320);
  float* macc = (float*)(wmem + 8576);
  const int m = select_neighbors<2048, 1024>(bpos, qx, qy, qz, 0.16f, wmem, jl);

  float* stg = (float*)wmem;  // [32][65]
  float* orow = out + (size_t)qid * 128;
  const float NEG = -__builtin_inff();
  const int fh = (lane & 1) * 64;

#pragma unroll 1
  for (int p = 0; p < 2; ++p) {
    const int n = p * 32 + (lane >> 1);
    const bool valid = n < m;
    const int j = valid ? (int)jl[n] : 0;
    const float rx = bpos[j * 3 + 0] - qx;
    const float ry = bpos[j * 3 + 1] - qy;
    const float rz = bpos[j * 3 + 2] - qz;
    const float* urow = u + ((size_t)b * 2048 + j) * 128 + fh;

    float y1[64];
#pragma unroll
    for (int t = 0; t < 64; t += 4) {
      float4 v = *reinterpret_cast<const float4*>(urow + t);
      y1[t] = v.x; y1[t + 1] = v.y; y1[t + 2] = v.z; y1[t + 3] = v.w;
    }
#pragma unroll
    for (int t = 0; t < 64; ++t) {
      float a = fmaf(rx, w1r[0 * 128 + fh + t], y1[t]);
      a = fmaf(ry, w1r[1 * 128 + fh + t], a);
      a = fmaf(rz, w1r[2 * 128 + fh + t], a);
      y1[t] = fmaxf(a, 0.0f);
    }

#pragma unroll 1
    for (int cst = 0; cst < 128; cst += 32) {
      lds_fence();
#pragma unroll 1
      for (int g = 0; g < 32; ++g) {
        const float* wrow = w2t + (size_t)(cst + g) * 128 + fh;  // 2-addr broadcast loads
        float a0 = 0.f, a1 = 0.f, a2 = 0.f, a3 = 0.f;
#pragma unroll
        for (int t = 0; t < 64; t += 4) {
          a0 = fmaf(y1[t], wrow[t], a0);
          a1 = fmaf(y1[t + 1], wrow[t + 1], a1);
          a2 = fmaf(y1[t + 2], wrow[t + 2], a2);
          a3 = fmaf(y1[t + 3], wrow[t + 3], a3);
        }
        float tot = (a0 + a1) + (a2 + a3);
        tot += __shfl_xor(tot, 1);  // pair-sum completes the 128-wide dot
        float h = b2[cst + g] + tot;
        stg[g * 65 + lane] = valid ? h : NEG;
      }
      lds_fence();
      const int r = lane & 31, jb = lane & 32;
      float mx = NEG;
#pragma unroll
      for (int t = 0; t < 32; ++t) mx = fmaxf(mx, stg[r * 65 + jb + t]);
      mx = fmaxf(mx, __shfl_xor(mx, 32));
      if (lane < 32) {
        if (p == 0) macc[cst + r] = mx;
        else orow[cst + r] = fmaxf(macc[cst + r], mx);
      }
    }
  }
}

// ---------------- fused stage kernels: blocks 0..7 = FPS, rest = conv ----------------
__global__ __launch_bounds__(256, 2) void stage1_kernel(
    const float* __restrict__ coords, const float* __restrict__ feats,
    const float* __restrict__ w1, const float* __restrict__ b1,
    const float* __restrict__ w2t, const float* __restrict__ b2,
    float* __restrict__ out, int* __restrict__ fps_idx, float* __restrict__ fps_pos) {
  __shared__ __align__(16) char smem[36352];  // fps: <29KB; conv: 4 x 9088
  if (blockIdx.x < 8) {
    fps_body<4096, 2048>(coords, (int)blockIdx.x, fps_idx, fps_pos, smem);
  } else {
    conv1_body(coords, feats, w1, b1, w2t, b2, out, ((int)blockIdx.x - 8) * 4 + WID,
               smem + WID * 9088);
  }
}

__global__ __launch_bounds__(256, 2) void stage2_kernel(
    const float* __restrict__ p1, const float* __restrict__ u2,
    const float* __restrict__ w1r, const float* __restrict__ w2t,
    const float* __restrict__ b2, float* __restrict__ out,
    int* __restrict__ fps_idx) {
  __shared__ __align__(16) char smem[36352];
  if (blockIdx.x < 8) {
    fps_body<2048, 512>(p1, (int)blockIdx.x, fps_idx, nullptr, smem);
  } else {
    conv2_body(p1, u2, w1r, w2t, b2, out, ((int)blockIdx.x - 8) * 4 + WID,
               smem + WID * 9088);
  }
}

// ------- u2 = b1b + h1[i1] @ W1b_feat (layer-1 factoring for stage 2) -------
__global__ __launch_bounds__(128) void u2_kernel(const float* __restrict__ h1,
                                                 const int* __restrict__ i1,
                                                 const float* __restrict__ w1,
                                                 const float* __restrict__ b1,
                                                 float* __restrict__ u2) {
  int row = blockIdx.x;  // 16384
  int f = (int)threadIdx.x;
  int b = row >> 11;
  int src = i1[row];
  const float* x = h1 + ((size_t)b * 4096 + src) * 64;
  float acc = b1[f];
#pragma unroll
  for (int k = 0; k < 64; ++k) acc = fmaf(x[k], w1[k * 128 + f], acc);
  u2[(size_t)row * 128 + f] = acc;
}

__global__ __launch_bounds__(256) void transpose_kernel(const float* __restrict__ w2a,
                                                        const float* __restrict__ w2b,
                                                        float* __restrict__ w2ta,
                                                        float* __restrict__ w2tb) {
  int gtid = blockIdx.x * 256 + (int)threadIdx.x;
  int stride = gridDim.x * 256;
  for (int t = gtid; t < 64 * 64; t += stride) w2ta[(t & 63) * 64 + (t >> 6)] = w2a[t];
  for (int t = gtid; t < 128 * 128; t += stride) w2tb[(t & 127) * 128 + (t >> 7)] = w2b[t];
}

// ---------------- global max pool over i2 + final linear ----------------
__global__ __launch_bounds__(512) void pool_linear_kernel(
    const float* __restrict__ h2, const int* __restrict__ i2,
    const float* __restrict__ wl, const float* __restrict__ bl,
    float* __restrict__ out) {
  int b = blockIdx.x;
  int c = (int)threadIdx.x >> 7;
  int f = (int)threadIdx.x & 127;
  __shared__ float part[4][128];
  __shared__ float feat[128];
  float mx = -__builtin_inff();
  const int* idx = i2 + b * 512;
  for (int s = c * 128; s < c * 128 + 128; ++s) {
    int j = idx[s];
    mx = fmaxf(mx, h2[((size_t)b * 2048 + j) * 128 + f]);
  }
  part[c][f] = mx;
  __syncthreads();
  if (c == 0) {
    feat[f] = fmaxf(fmaxf(part[0][f], part[1][f]), fmaxf(part[2][f], part[3][f]));
  }
  __syncthreads();
  if (c == 0) {
    float acc = bl[f];
#pragma unroll
    for (int k = 0; k < 128; ++k) acc = fmaf(feat[k], wl[k * 128 + f], acc);
    out[b * 128 + f] = acc;
  }
}

extern "C" void kernel_launch(void* const* d_in, const int* in_sizes, int n_in,
                              void* d_out, int out_size, void* d_ws, size_t ws_size,
                              hipStream_t stream) {
  const float* feats = (const float*)d_in[0];   // [8,4096,6]
  const float* coords = (const float*)d_in[1];  // [8,4096,3]
  const float* W1a = (const float*)d_in[2];     // [9,64]
  const float* b1a = (const float*)d_in[3];
  const float* W2a = (const float*)d_in[4];     // [64,64]
  const float* b2a = (const float*)d_in[5];
  const float* W1b = (const float*)d_in[6];     // [67,128]
  const float* b1b = (const float*)d_in[7];
  const float* W2b = (const float*)d_in[8];     // [128,128]
  const float* b2b = (const float*)d_in[9];
  const float* Wl = (const float*)d_in[10];     // [128,128]
  const float* bl = (const float*)d_in[11];

  float* ws = (float*)d_ws;
  float* W2TA = ws;                  // 4096
  float* W2TB = W2TA + 4096;         // 16384
  float* H1 = W2TB + 16384;          // 8*4096*64  = 2097152
  float* U2 = H1 + 2097152;          // 8*2048*128 = 2097152
  float* H2 = U2 + 2097152;          // 8*2048*128 = 2097152
  float* P1 = H2 + 2097152;          // 8*2048*3   = 49152
  int* I1 = (int*)(P1 + 49152);      // 8*2048
  int* I2 = I1 + 16384;              // 8*512

  transpose_kernel<<<80, 256, 0, stream>>>(W2a, W2b, W2TA, W2TB);
  // stage 1: fps1 (blocks 0-7) || conv1 (8192 blocks)
  stage1_kernel<<<8 + 8192, 256, 0, stream>>>(coords, feats, W1a, b1a, W2TA, b2a, H1,
                                              I1, P1);
  u2_kernel<<<16384, 128, 0, stream>>>(H1, I1, W1b, b1b, U2);
  // stage 2: fps2 (blocks 0-7) || conv2 (4096 blocks)
  stage2_kernel<<<8 + 4096, 256, 0, stream>>>(P1, U2, W1b + 64 * 128, W2TB, b2b, H2, I2);
  pool_linear_kernel<<<8, 512, 0, stream>>>(H2, I2, Wl, bl, (float*)d_out);
}

// Round 4
// 4411.062 us; speedup vs baseline: 1.4425x; 1.3954x over previous
//
#include <hip/hip_runtime.h>
#include <stdint.h>

#define LANE ((int)(threadIdx.x & 63))
#define WID  ((int)(threadIdx.x >> 6))

__device__ __forceinline__ float exact_d2(float ax, float ay, float az,
                                          float bx, float by, float bz) {
  float dx = ax - bx, dy = ay - by, dz = az - bz;
  return __fadd_rn(__fadd_rn(__fmul_rn(dx, dx), __fmul_rn(dy, dy)), __fmul_rn(dz, dz));
}

__device__ __forceinline__ void lds_fence() {
  asm volatile("s_waitcnt lgkmcnt(0)" ::: "memory");
}

// ---------------- FPS body: 512 threads, one block per batch, 1 barrier/iter ------
// Per iter: update dd (winner coords carried in regs) -> f32 butterfly max ->
// ballot+ffs gives first-index wave winner -> winner publishes u64 key (dist bits,
// NPTS-1-idx) + coords to parity slot -> barrier -> pick best of 8 wave keys.
template <int NPTS, int NSAMP>
__device__ void fps_body(const float* __restrict__ coords, int b,
                         int* __restrict__ out_idx, float* __restrict__ out_pos,
                         char* smem_raw) {
  constexpr int PT = NPTS / 512;
  uint64_t* swk = (uint64_t*)smem_raw;                         // [2][8] keys
  float* swc = (float*)(swk + 16);                             // [2][8][4] coords
  float* spos = swc + 64;                                      // [NSAMP*3]
  unsigned short* sidx = (unsigned short*)(spos + NSAMP * 3);  // [NSAMP]
  const float* pos = coords + (size_t)b * NPTS * 3;
  const int tid = (int)threadIdx.x;
  const int lane = LANE, wid = WID;

  __builtin_amdgcn_s_setprio(1);  // FPS is the serial critical path

  float px[PT], py[PT], pz[PT], dd[PT];
  const int i0 = tid * PT;
#pragma unroll
  for (int k = 0; k < PT; ++k) {
    px[k] = pos[(i0 + k) * 3 + 0];
    py[k] = pos[(i0 + k) * 3 + 1];
    pz[k] = pos[(i0 + k) * 3 + 2];
    dd[k] = __builtin_inff();
  }
  float fx = pos[0], fy = pos[1], fz = pos[2];
  if (tid == 0) {
    sidx[0] = 0;
    spos[0] = fx; spos[1] = fy; spos[2] = fz;
  }
  __syncthreads();

  for (int s = 1; s < NSAMP; ++s) {
    float lv = -__builtin_inff();
    int bestk = 0;
#pragma unroll
    for (int k = 0; k < PT; ++k) {
      float d = exact_d2(px[k], py[k], pz[k], fx, fy, fz);
      dd[k] = fminf(dd[k], d);
      if (dd[k] > lv) { lv = dd[k]; bestk = k; }  // strict >: first index in thread
    }
    float wv = lv;
#pragma unroll
    for (int off = 1; off < 64; off <<= 1) wv = fmaxf(wv, __shfl_xor(wv, off));
    const uint64_t mask = __ballot(lv == wv);
    const int wl = (int)__ffsll((unsigned long long)mask) - 1;  // lowest lane = min idx
    const int par = s & 1;
    if (lane == wl) {  // wave winner publishes key + coords pre-barrier
      swk[par * 8 + wid] =
          ((uint64_t)__float_as_uint(wv) << 32) | (unsigned)(NPTS - 1 - (i0 + bestk));
      float* c = swc + (par * 8 + wid) * 4;
      c[0] = px[bestk]; c[1] = py[bestk]; c[2] = pz[bestk];
    }
    __syncthreads();
    uint64_t kk = swk[par * 8];
    int w = 0;
#pragma unroll
    for (int ww = 1; ww < 8; ++ww) {
      uint64_t kw = swk[par * 8 + ww];
      if (kw > kk) { kk = kw; w = ww; }
    }
    const float* c = swc + (par * 8 + w) * 4;
    fx = c[0]; fy = c[1]; fz = c[2];
    if (wid == w && lane == wl) {  // unique global winner records outputs
      sidx[s] = (unsigned short)(i0 + bestk);
      spos[s * 3 + 0] = px[bestk];
      spos[s * 3 + 1] = py[bestk];
      spos[s * 3 + 2] = pz[bestk];
    }
  }
  __syncthreads();
  for (int s = tid; s < NSAMP; s += 512) {
    out_idx[(size_t)b * NSAMP + s] = (int)sidx[s];
    if (out_pos) {
      out_pos[((size_t)b * NSAMP + s) * 3 + 0] = spos[s * 3 + 0];
      out_pos[((size_t)b * NSAMP + s) * 3 + 1] = spos[s * 3 + 1];
      out_pos[((size_t)b * NSAMP + s) * 3 + 2] = spos[s * 3 + 2];
    }
  }
}

// ---- exact neighbor selection: in-radius candidates, 64 nearest (d, then j) ----
template <int NPTS, int CAP>
__device__ __forceinline__ int select_neighbors(const float* __restrict__ bpos,
                                                float qx, float qy, float qz, float r2,
                                                char* wmem, unsigned* jl) {
  constexpr int SLOTS = CAP / 64;
  const int lane = LANE;
  uint64_t* list = (uint64_t*)wmem;
  const uint64_t ltmask = (1ull << lane) - 1ull;

  unsigned cnt = 0;
  for (int base = 0; base < NPTS; base += 64) {
    int j = base + lane;
    float d = exact_d2(bpos[j * 3], bpos[j * 3 + 1], bpos[j * 3 + 2], qx, qy, qz);
    bool pred = d < r2;
    uint64_t mask = __ballot(pred);
    if (pred) {
      unsigned p = cnt + (unsigned)__popcll(mask & ltmask);
      if (p < CAP) list[p] = ((uint64_t)__float_as_uint(d) << 32) | (unsigned)j;
    }
    cnt += (unsigned)__popcll(mask);
  }
  if (cnt > CAP) cnt = CAP;
  lds_fence();

  int m;
  if (cnt <= 64) {
    m = (int)cnt;
    jl[lane] = (lane < m) ? (unsigned)list[lane] : 0u;
  } else {
    m = 64;
    uint64_t e[SLOTS];
#pragma unroll
    for (int si = 0; si < SLOTS; ++si) {
      int p = lane + 64 * si;
      e[si] = (p < (int)cnt) ? list[p] : ~0ull;
    }
    // binary search for d* = 64th smallest distance bit-pattern
    unsigned lo = 0, hi = 0x3F800000u;
    while (lo < hi) {
      unsigned mid = (lo + hi) >> 1;
      unsigned c = 0;
#pragma unroll
      for (int si = 0; si < SLOTS; ++si)
        c += (unsigned)__popcll(__ballot((unsigned)(e[si] >> 32) <= mid));
      if (c >= 64u) hi = mid; else lo = mid + 1;
    }
    const unsigned dstar = lo;
    unsigned nlt = 0, nt = 0;
#pragma unroll
    for (int si = 0; si < SLOTS; ++si) {
      unsigned hb = (unsigned)(e[si] >> 32);
      nlt += (unsigned)__popcll(__ballot(hb < dstar));
      nt += (unsigned)__popcll(__ballot(hb == dstar));
    }
    const unsigned need = 64u - nlt;
    unsigned jsel = 0xFFFFFFFFu;
    if (nt != need) {  // distance tie at the cut -> keep `need` smallest j
      unsigned jlo = 0, jhi = (unsigned)NPTS - 1;
      while (jlo < jhi) {
        unsigned jmid = (jlo + jhi) >> 1;
        unsigned c = 0;
#pragma unroll
        for (int si = 0; si < SLOTS; ++si)
          c += (unsigned)__popcll(__ballot(
              ((unsigned)(e[si] >> 32) == dstar) && ((unsigned)e[si] <= jmid)));
        if (c >= need) jhi = jmid; else jlo = jmid + 1;
      }
      jsel = jlo;
    }
    unsigned c2 = 0;
#pragma unroll
    for (int si = 0; si < SLOTS; ++si) {
      unsigned hb = (unsigned)(e[si] >> 32), jj = (unsigned)e[si];
      bool p = (hb < dstar) || ((hb == dstar) && (jj <= jsel));
      uint64_t mask = __ballot(p);
      if (p) jl[c2 + (unsigned)__popcll(mask & ltmask)] = jj;
      c2 += (unsigned)__popcll(mask);
    }
  }
  lds_fence();
  return m;
}

// ---------------- conv1: H=64, lane = neighbor, y1[64] in regs ----------------
__device__ void conv1_body(const float* __restrict__ pos, const float* __restrict__ feats,
                           const float* __restrict__ w1, const float* __restrict__ b1,
                           const float* __restrict__ w2t, const float* __restrict__ b2,
                           float* __restrict__ out, int qid, char* wmem) {
  const int lane = LANE;
  const int b = qid >> 12, qi = qid & 4095;
  const float* bpos = pos + (size_t)b * 4096 * 3;
  const float qx = bpos[qi * 3 + 0], qy = bpos[qi * 3 + 1], qz = bpos[qi * 3 + 2];
  unsigned* jl = (unsigned*)(wmem + 8320);
  const int m = select_neighbors<4096, 512>(bpos, qx, qy, qz, 0.04f, wmem, jl);

  const bool valid = lane < m;
  const int j = valid ? (int)jl[lane] : 0;
  const float rx = bpos[j * 3 + 0] - qx;
  const float ry = bpos[j * 3 + 1] - qy;
  const float rz = bpos[j * 3 + 2] - qz;
  const float* xr = feats + ((size_t)b * 4096 + j) * 6;
  const float x0 = xr[0], x1 = xr[1], x2 = xr[2], x3 = xr[3], x4 = xr[4], x5 = xr[5];
  const float* w1r = w1 + 6 * 64;

  float y1[64];
#pragma unroll
  for (int f = 0; f < 64; ++f) {
    float a = b1[f];
    a = fmaf(x0, w1[0 * 64 + f], a);
    a = fmaf(x1, w1[1 * 64 + f], a);
    a = fmaf(x2, w1[2 * 64 + f], a);
    a = fmaf(x3, w1[3 * 64 + f], a);
    a = fmaf(x4, w1[4 * 64 + f], a);
    a = fmaf(x5, w1[5 * 64 + f], a);
    a = fmaf(rx, w1r[0 * 64 + f], a);
    a = fmaf(ry, w1r[1 * 64 + f], a);
    a = fmaf(rz, w1r[2 * 64 + f], a);
    y1[f] = fmaxf(a, 0.0f);
  }

  float* stg = (float*)wmem;  // [32][65], reuses candidate area
  float* orow = out + (size_t)qid * 64;
  const float NEG = -__builtin_inff();
#pragma unroll 1
  for (int cst = 0; cst < 64; cst += 32) {
    lds_fence();
#pragma unroll 1
    for (int g = 0; g < 32; ++g) {
      const float* wrow = w2t + (size_t)(cst + g) * 64;  // uniform -> s_load
      float a0 = 0.f, a1 = 0.f, a2 = 0.f, a3 = 0.f;
#pragma unroll
      for (int f = 0; f < 64; f += 4) {
        a0 = fmaf(y1[f], wrow[f], a0);
        a1 = fmaf(y1[f + 1], wrow[f + 1], a1);
        a2 = fmaf(y1[f + 2], wrow[f + 2], a2);
        a3 = fmaf(y1[f + 3], wrow[f + 3], a3);
      }
      float acc = b2[cst + g] + ((a0 + a1) + (a2 + a3));
      stg[g * 65 + lane] = valid ? acc : NEG;
    }
    lds_fence();
    const int r = lane & 31, jb = lane & 32;
    float mx = NEG;
#pragma unroll
    for (int t = 0; t < 32; ++t) mx = fmaxf(mx, stg[r * 65 + jb + t]);
    mx = fmaxf(mx, __shfl_xor(mx, 32));
    if (lane < 32) orow[cst + lane] = mx;
  }
}

// ------- conv2: H=128, TWO waves per query (wave-uniform feature half) -------
// Wave half h covers features fh..fh+63 for all 64 neighbors (lane = neighbor).
// wrow pointer is wave-uniform (readfirstlane'd fh) -> s_load weight rows.
// Halves combine in LDS: comb = pA + pB, transpose-max, +b2 after max (bitwise-equal).
__device__ void conv2_body(const float* __restrict__ pos, const float* __restrict__ u,
                           const float* __restrict__ w1r, const float* __restrict__ w2t,
                           const float* __restrict__ b2, float* __restrict__ out,
                           int qid, int half, char* wmem, char* pairmem) {
  const int lane = LANE;
  const int b = qid >> 11, qi = qid & 2047;
  const float* bpos = pos + (size_t)b * 2048 * 3;
  const float qx = bpos[qi * 3 + 0], qy = bpos[qi * 3 + 1], qz = bpos[qi * 3 + 2];
  unsigned* jl = (unsigned*)(wmem + 8320);
  const int m = select_neighbors<2048, 1024>(bpos, qx, qy, qz, 0.16f, wmem, jl);
  const int fh = half * 64;

  const bool valid = lane < m;
  const int j = valid ? (int)jl[lane] : 0;
  const float rx = bpos[j * 3 + 0] - qx;
  const float ry = bpos[j * 3 + 1] - qy;
  const float rz = bpos[j * 3 + 2] - qz;
  const float* urow = u + ((size_t)b * 2048 + j) * 128 + fh;

  float y1[64];
#pragma unroll
  for (int t = 0; t < 64; t += 4) {
    float4 v = *reinterpret_cast<const float4*>(urow + t);
    y1[t] = v.x; y1[t + 1] = v.y; y1[t + 2] = v.z; y1[t + 3] = v.w;
  }
#pragma unroll
  for (int t = 0; t < 64; ++t) {
    float a = fmaf(rx, w1r[0 * 128 + fh + t], y1[t]);
    a = fmaf(ry, w1r[1 * 128 + fh + t], a);
    a = fmaf(rz, w1r[2 * 128 + fh + t], a);
    y1[t] = fmaxf(a, 0.0f);
  }

  float* stgA = (float*)pairmem;           // half-0 wave's [32][65]
  float* stgB = (float*)(pairmem + 8704);  // half-1 wave's [32][65]
  float* stg_own = half ? stgB : stgA;     // == wmem
  float* orow = out + (size_t)qid * 128;
  const float NEG = -__builtin_inff();
#pragma unroll 1
  for (int cst = 0; cst < 128; cst += 32) {
#pragma unroll 1
    for (int g = 0; g < 32; ++g) {
      const float* wrow = w2t + (size_t)(cst + g) * 128 + fh;  // uniform -> s_load
      float a0 = 0.f, a1 = 0.f, a2 = 0.f, a3 = 0.f;
#pragma unroll
      for (int t = 0; t < 64; t += 4) {
        a0 = fmaf(y1[t], wrow[t], a0);
        a1 = fmaf(y1[t + 1], wrow[t + 1], a1);
        a2 = fmaf(y1[t + 2], wrow[t + 2], a2);
        a3 = fmaf(y1[t + 3], wrow[t + 3], a3);
      }
      float pc = (a0 + a1) + (a2 + a3);
      stg_own[g * 65 + lane] = valid ? pc : (half ? 0.0f : NEG);
    }
    __syncthreads();
    if (half == 0) {
      const int r = lane & 31, jb = (lane >> 5) * 32;
      float mx = NEG;
#pragma unroll
      for (int t = 0; t < 32; ++t)
        mx = fmaxf(mx, stgA[r * 65 + jb + t] + stgB[r * 65 + jb + t]);
      mx = fmaxf(mx, __shfl_xor(mx, 32));
      if (lane < 32) orow[cst + lane] = mx + b2[cst + lane];
    }
    __syncthreads();
  }
}

// ---------------- fused stage kernels: blocks 0..7 = FPS, rest = conv ----------------
__global__ __launch_bounds__(512, 4) void stage1_kernel(
    const float* __restrict__ coords, const float* __restrict__ feats,
    const float* __restrict__ w1, const float* __restrict__ b1,
    const float* __restrict__ w2t, const float* __restrict__ b2,
    float* __restrict__ out, int* __restrict__ fps_idx, float* __restrict__ fps_pos) {
  __shared__ __align__(16) char smem[69632];  // fps: <29KB; conv: 8 x 8704
  if (blockIdx.x < 8) {
    fps_body<4096, 2048>(coords, (int)blockIdx.x, fps_idx, fps_pos, smem);
  } else {
    int qid = __builtin_amdgcn_readfirstlane(((int)blockIdx.x - 8) * 8 + WID);
    conv1_body(coords, feats, w1, b1, w2t, b2, out, qid, smem + WID * 8704);
  }
}

__global__ __launch_bounds__(512, 4) void stage2_kernel(
    const float* __restrict__ p1, const float* __restrict__ u2,
    const float* __restrict__ w1r, const float* __restrict__ w2t,
    const float* __restrict__ b2, float* __restrict__ out,
    int* __restrict__ fps_idx) {
  __shared__ __align__(16) char smem[69632];
  if (blockIdx.x < 8) {
    fps_body<2048, 512>(p1, (int)blockIdx.x, fps_idx, nullptr, smem);
  } else {
    const int wid = WID;
    const int half = __builtin_amdgcn_readfirstlane(wid & 1);
    const int qid = __builtin_amdgcn_readfirstlane(((int)blockIdx.x - 8) * 4 + (wid >> 1));
    conv2_body(p1, u2, w1r, w2t, b2, out, qid, half, smem + wid * 8704,
               smem + (wid & ~1) * 8704);
  }
}

// ------- u2 = b1b + h1[i1] @ W1b_feat (layer-1 factoring for stage 2) -------
__global__ __launch_bounds__(128) void u2_kernel(const float* __restrict__ h1,
                                                 const int* __restrict__ i1,
                                                 const float* __restrict__ w1,
                                                 const float* __restrict__ b1,
                                                 float* __restrict__ u2) {
  int row = blockIdx.x;  // 16384
  int f = (int)threadIdx.x;
  int b = row >> 11;
  int src = i1[row];
  const float* x = h1 + ((size_t)b * 4096 + src) * 64;
  float acc = b1[f];
#pragma unroll
  for (int k = 0; k < 64; ++k) acc = fmaf(x[k], w1[k * 128 + f], acc);
  u2[(size_t)row * 128 + f] = acc;
}

__global__ __launch_bounds__(256) void transpose_kernel(const float* __restrict__ w2a,
                                                        const float* __restrict__ w2b,
                                                        float* __restrict__ w2ta,
                                                        float* __restrict__ w2tb) {
  int gtid = blockIdx.x * 256 + (int)threadIdx.x;
  int stride = gridDim.x * 256;
  for (int t = gtid; t < 64 * 64; t += stride) w2ta[(t & 63) * 64 + (t >> 6)] = w2a[t];
  for (int t = gtid; t < 128 * 128; t += stride) w2tb[(t & 127) * 128 + (t >> 7)] = w2b[t];
}

// ---------------- global max pool over i2 + final linear ----------------
__global__ __launch_bounds__(512) void pool_linear_kernel(
    const float* __restrict__ h2, const int* __restrict__ i2,
    const float* __restrict__ wl, const float* __restrict__ bl,
    float* __restrict__ out) {
  int b = blockIdx.x;
  int c = (int)threadIdx.x >> 7;
  int f = (int)threadIdx.x & 127;
  __shared__ float part[4][128];
  __shared__ float feat[128];
  float mx = -__builtin_inff();
  const int* idx = i2 + b * 512;
  for (int s = c * 128; s < c * 128 + 128; ++s) {
    int j = idx[s];
    mx = fmaxf(mx, h2[((size_t)b * 2048 + j) * 128 + f]);
  }
  part[c][f] = mx;
  __syncthreads();
  if (c == 0) {
    feat[f] = fmaxf(fmaxf(part[0][f], part[1][f]), fmaxf(part[2][f], part[3][f]));
  }
  __syncthreads();
  if (c == 0) {
    float acc = bl[f];
#pragma unroll
    for (int k = 0; k < 128; ++k) acc = fmaf(feat[k], wl[k * 128 + f], acc);
    out[b * 128 + f] = acc;
  }
}

extern "C" void kernel_launch(void* const* d_in, const int* in_sizes, int n_in,
                              void* d_out, int out_size, void* d_ws, size_t ws_size,
                              hipStream_t stream) {
  const float* feats = (const float*)d_in[0];   // [8,4096,6]
  const float* coords = (const float*)d_in[1];  // [8,4096,3]
  const float* W1a = (const float*)d_in[2];     // [9,64]
  const float* b1a = (const float*)d_in[3];
  const float* W2a = (const float*)d_in[4];     // [64,64]
  const float* b2a = (const float*)d_in[5];
  const float* W1b = (const float*)d_in[6];     // [67,128]
  const float* b1b = (const float*)d_in[7];
  const float* W2b = (const float*)d_in[8];     // [128,128]
  const float* b2b = (const float*)d_in[9];
  const float* Wl = (const float*)d_in[10];     // [128,128]
  const float* bl = (const float*)d_in[11];

  float* ws = (float*)d_ws;
  float* W2TA = ws;                  // 4096
  float* W2TB = W2TA + 4096;         // 16384
  float* H1 = W2TB + 16384;          // 8*4096*64  = 2097152
  float* U2 = H1 + 2097152;          // 8*2048*128 = 2097152
  float* H2 = U2 + 2097152;          // 8*2048*128 = 2097152
  float* P1 = H2 + 2097152;          // 8*2048*3   = 49152
  int* I1 = (int*)(P1 + 49152);      // 8*2048
  int* I2 = I1 + 16384;              // 8*512

  transpose_kernel<<<80, 256, 0, stream>>>(W2a, W2b, W2TA, W2TB);
  // stage 1: fps1 (blocks 0-7, 512 thr) || conv1 (4096 blocks x 8 queries)
  stage1_kernel<<<8 + 4096, 512, 0, stream>>>(coords, feats, W1a, b1a, W2TA, b2a, H1,
                                              I1, P1);
  u2_kernel<<<16384, 128, 0, stream>>>(H1, I1, W1b, b1b, U2);
  // stage 2: fps2 (blocks 0-7) || conv2 (4096 blocks x 4 queries x 2 waves)
  stage2_kernel<<<8 + 4096, 512, 0, stream>>>(P1, U2, W1b + 64 * 128, W2TB, b2b, H2, I2);
  pool_linear_kernel<<<8, 512, 0, stream>>>(H2, I2, Wl, bl, (float*)d_out);
}

// Round 5
// 2994.910 us; speedup vs baseline: 2.1246x; 1.4729x over previous
//
#include <hip/hip_runtime.h>
#include <stdint.h>

#define LANE ((int)(threadIdx.x & 63))
#define WID  ((int)(threadIdx.x >> 6))

__device__ __forceinline__ float exact_d2(float ax, float ay, float az,
                                          float bx, float by, float bz) {
  float dx = ax - bx, dy = ay - by, dz = az - bz;
  return __fadd_rn(__fadd_rn(__fmul_rn(dx, dx), __fmul_rn(dy, dy)), __fmul_rn(dz, dz));
}

__device__ __forceinline__ void lds_fence() {
  asm volatile("s_waitcnt lgkmcnt(0)" ::: "memory");
}

// ---------------- FPS body: 256 threads, one block per batch, 1 barrier/iter ------
// Per iter: update dd (winner coords carried in regs) -> f32 butterfly max ->
// ballot+ffs gives first-index wave winner -> winner publishes u64 key (dist bits,
// NPTS-1-idx) + coords to parity slot -> barrier -> pick best of 4 wave keys.
template <int NPTS, int NSAMP>
__device__ void fps_body(const float* __restrict__ coords, int b,
                         int* __restrict__ out_idx, float* __restrict__ out_pos,
                         char* smem_raw) {
  constexpr int PT = NPTS / 256;
  uint64_t* swk = (uint64_t*)smem_raw;                         // [2][4] keys
  float* swc = (float*)(swk + 8);                              // [2][4][4] coords
  float* spos = swc + 32;                                      // [NSAMP*3]
  unsigned short* sidx = (unsigned short*)(spos + NSAMP * 3);  // [NSAMP]
  const float* pos = coords + (size_t)b * NPTS * 3;
  const int tid = (int)threadIdx.x;
  const int lane = LANE, wid = WID;

  __builtin_amdgcn_s_setprio(1);  // FPS is the serial critical path

  float px[PT], py[PT], pz[PT], dd[PT];
  const int i0 = tid * PT;
#pragma unroll
  for (int k = 0; k < PT; ++k) {
    px[k] = pos[(i0 + k) * 3 + 0];
    py[k] = pos[(i0 + k) * 3 + 1];
    pz[k] = pos[(i0 + k) * 3 + 2];
    dd[k] = __builtin_inff();
  }
  float fx = pos[0], fy = pos[1], fz = pos[2];
  if (tid == 0) {
    sidx[0] = 0;
    spos[0] = fx; spos[1] = fy; spos[2] = fz;
  }
  __syncthreads();

  for (int s = 1; s < NSAMP; ++s) {
    float lv = -__builtin_inff();
    int bestk = 0;
#pragma unroll
    for (int k = 0; k < PT; ++k) {
      float d = exact_d2(px[k], py[k], pz[k], fx, fy, fz);
      dd[k] = fminf(dd[k], d);
      if (dd[k] > lv) { lv = dd[k]; bestk = k; }  // strict >: first index in thread
    }
    float wv = lv;
#pragma unroll
    for (int off = 1; off < 64; off <<= 1) wv = fmaxf(wv, __shfl_xor(wv, off));
    const uint64_t mask = __ballot(lv == wv);
    const int wl = (int)__ffsll((unsigned long long)mask) - 1;  // lowest lane = min idx
    const int par = s & 1;
    if (lane == wl) {  // wave winner publishes key + coords pre-barrier
      swk[par * 4 + wid] =
          ((uint64_t)__float_as_uint(wv) << 32) | (unsigned)(NPTS - 1 - (i0 + bestk));
      float* c = swc + (par * 4 + wid) * 4;
      c[0] = px[bestk]; c[1] = py[bestk]; c[2] = pz[bestk];
    }
    __syncthreads();
    uint64_t kk = swk[par * 4];
    int w = 0;
#pragma unroll
    for (int ww = 1; ww < 4; ++ww) {
      uint64_t kw = swk[par * 4 + ww];
      if (kw > kk) { kk = kw; w = ww; }
    }
    const float* c = swc + (par * 4 + w) * 4;
    fx = c[0]; fy = c[1]; fz = c[2];
    if (wid == w && lane == wl) {  // unique global winner records outputs
      sidx[s] = (unsigned short)(i0 + bestk);
      spos[s * 3 + 0] = px[bestk];
      spos[s * 3 + 1] = py[bestk];
      spos[s * 3 + 2] = pz[bestk];
    }
  }
  __syncthreads();
  for (int s = tid; s < NSAMP; s += 256) {
    out_idx[(size_t)b * NSAMP + s] = (int)sidx[s];
    if (out_pos) {
      out_pos[((size_t)b * NSAMP + s) * 3 + 0] = spos[s * 3 + 0];
      out_pos[((size_t)b * NSAMP + s) * 3 + 1] = spos[s * 3 + 1];
      out_pos[((size_t)b * NSAMP + s) * 3 + 2] = spos[s * 3 + 2];
    }
  }
}

// ---- exact neighbor selection: in-radius candidates, 64 nearest (d, then j) ----
template <int NPTS, int CAP>
__device__ __forceinline__ int select_neighbors(const float* __restrict__ bpos,
                                                float qx, float qy, float qz, float r2,
                                                char* wmem, unsigned* jl) {
  constexpr int SLOTS = CAP / 64;
  const int lane = LANE;
  uint64_t* list = (uint64_t*)wmem;
  const uint64_t ltmask = (1ull << lane) - 1ull;

  unsigned cnt = 0;
  for (int base = 0; base < NPTS; base += 64) {
    int j = base + lane;
    float d = exact_d2(bpos[j * 3], bpos[j * 3 + 1], bpos[j * 3 + 2], qx, qy, qz);
    bool pred = d < r2;
    uint64_t mask = __ballot(pred);
    if (pred) {
      unsigned p = cnt + (unsigned)__popcll(mask & ltmask);
      if (p < CAP) list[p] = ((uint64_t)__float_as_uint(d) << 32) | (unsigned)j;
    }
    cnt += (unsigned)__popcll(mask);
  }
  if (cnt > CAP) cnt = CAP;
  lds_fence();

  int m;
  if (cnt <= 64) {
    m = (int)cnt;
    jl[lane] = (lane < m) ? (unsigned)list[lane] : 0u;
  } else {
    m = 64;
    uint64_t e[SLOTS];
#pragma unroll
    for (int si = 0; si < SLOTS; ++si) {
      int p = lane + 64 * si;
      e[si] = (p < (int)cnt) ? list[p] : ~0ull;
    }
    // binary search for d* = 64th smallest distance bit-pattern
    unsigned lo = 0, hi = 0x3F800000u;
    while (lo < hi) {
      unsigned mid = (lo + hi) >> 1;
      unsigned c = 0;
#pragma unroll
      for (int si = 0; si < SLOTS; ++si)
        c += (unsigned)__popcll(__ballot((unsigned)(e[si] >> 32) <= mid));
      if (c >= 64u) hi = mid; else lo = mid + 1;
    }
    const unsigned dstar = lo;
    unsigned nlt = 0, nt = 0;
#pragma unroll
    for (int si = 0; si < SLOTS; ++si) {
      unsigned hb = (unsigned)(e[si] >> 32);
      nlt += (unsigned)__popcll(__ballot(hb < dstar));
      nt += (unsigned)__popcll(__ballot(hb == dstar));
    }
    const unsigned need = 64u - nlt;
    unsigned jsel = 0xFFFFFFFFu;
    if (nt != need) {  // distance tie at the cut -> keep `need` smallest j
      unsigned jlo = 0, jhi = (unsigned)NPTS - 1;
      while (jlo < jhi) {
        unsigned jmid = (jlo + jhi) >> 1;
        unsigned c = 0;
#pragma unroll
        for (int si = 0; si < SLOTS; ++si)
          c += (unsigned)__popcll(__ballot(
              ((unsigned)(e[si] >> 32) == dstar) && ((unsigned)e[si] <= jmid)));
        if (c >= need) jhi = jmid; else jlo = jmid + 1;
      }
      jsel = jlo;
    }
    unsigned c2 = 0;
#pragma unroll
    for (int si = 0; si < SLOTS; ++si) {
      unsigned hb = (unsigned)(e[si] >> 32), jj = (unsigned)e[si];
      bool p = (hb < dstar) || ((hb == dstar) && (jj <= jsel));
      uint64_t mask = __ballot(p);
      if (p) jl[c2 + (unsigned)__popcll(mask & ltmask)] = jj;
      c2 += (unsigned)__popcll(mask);
    }
  }
  lds_fence();
  return m;
}

// ---------------- conv1: H=64, lane = neighbor, y1[64] in regs ----------------
__device__ void conv1_body(const float* __restrict__ pos, const float* __restrict__ feats,
                           const float* __restrict__ w1, const float* __restrict__ b1,
                           const float* __restrict__ w2t, const float* __restrict__ b2,
                           float* __restrict__ out, int qid, char* wmem) {
  const int lane = LANE;
  const int b = qid >> 12, qi = qid & 4095;
  const float* bpos = pos + (size_t)b * 4096 * 3;
  const float qx = bpos[qi * 3 + 0], qy = bpos[qi * 3 + 1], qz = bpos[qi * 3 + 2];
  unsigned* jl = (unsigned*)(wmem + 8320);
  const int m = select_neighbors<4096, 512>(bpos, qx, qy, qz, 0.04f, wmem, jl);

  const bool valid = lane < m;
  const int j = valid ? (int)jl[lane] : 0;
  const float rx = bpos[j * 3 + 0] - qx;
  const float ry = bpos[j * 3 + 1] - qy;
  const float rz = bpos[j * 3 + 2] - qz;
  const float* xr = feats + ((size_t)b * 4096 + j) * 6;
  const float x0 = xr[0], x1 = xr[1], x2 = xr[2], x3 = xr[3], x4 = xr[4], x5 = xr[5];
  const float* w1r = w1 + 6 * 64;

  float y1[64];
#pragma unroll
  for (int f = 0; f < 64; ++f) {
    float a = b1[f];
    a = fmaf(x0, w1[0 * 64 + f], a);
    a = fmaf(x1, w1[1 * 64 + f], a);
    a = fmaf(x2, w1[2 * 64 + f], a);
    a = fmaf(x3, w1[3 * 64 + f], a);
    a = fmaf(x4, w1[4 * 64 + f], a);
    a = fmaf(x5, w1[5 * 64 + f], a);
    a = fmaf(rx, w1r[0 * 64 + f], a);
    a = fmaf(ry, w1r[1 * 64 + f], a);
    a = fmaf(rz, w1r[2 * 64 + f], a);
    y1[f] = fmaxf(a, 0.0f);
  }

  float* stg = (float*)wmem;  // [32][65], reuses candidate area
  float* orow = out + (size_t)qid * 64;
  const float NEG = -__builtin_inff();
#pragma unroll 1
  for (int cst = 0; cst < 64; cst += 32) {
    lds_fence();
#pragma unroll 1
    for (int g = 0; g < 32; ++g) {
      const float* wrow = w2t + (size_t)(cst + g) * 64;  // uniform -> s_load
      float a0 = 0.f, a1 = 0.f, a2 = 0.f, a3 = 0.f;
#pragma unroll
      for (int f = 0; f < 64; f += 4) {
        a0 = fmaf(y1[f], wrow[f], a0);
        a1 = fmaf(y1[f + 1], wrow[f + 1], a1);
        a2 = fmaf(y1[f + 2], wrow[f + 2], a2);
        a3 = fmaf(y1[f + 3], wrow[f + 3], a3);
      }
      float acc = b2[cst + g] + ((a0 + a1) + (a2 + a3));
      stg[g * 65 + lane] = valid ? acc : NEG;
    }
    lds_fence();
    const int r = lane & 31, jb = lane & 32;
    float mx = NEG;
#pragma unroll
    for (int t = 0; t < 32; ++t) mx = fmaxf(mx, stg[r * 65 + jb + t]);
    mx = fmaxf(mx, __shfl_xor(mx, 32));
    if (lane < 32) orow[cst + lane] = mx;
  }
}

// ------- conv2: H=128, TWO waves per query (wave-uniform feature half) -------
// Wave half h covers features fh..fh+63 for all 64 neighbors (lane = neighbor).
// wrow pointer is wave-uniform -> s_load weight rows. Halves combine in LDS:
// comb = pA + pB, transpose-max, +b2 after max (bitwise-equal by monotonicity).
__device__ void conv2_body(const float* __restrict__ pos, const float* __restrict__ u,
                           const float* __restrict__ w1r, const float* __restrict__ w2t,
                           const float* __restrict__ b2, float* __restrict__ out,
                           int qid, int half, char* wmem, char* pairmem) {
  const int lane = LANE;
  const int b = qid >> 11, qi = qid & 2047;
  const float* bpos = pos + (size_t)b * 2048 * 3;
  const float qx = bpos[qi * 3 + 0], qy = bpos[qi * 3 + 1], qz = bpos[qi * 3 + 2];
  unsigned* jl = (unsigned*)(wmem + 8320);
  const int m = select_neighbors<2048, 1024>(bpos, qx, qy, qz, 0.16f, wmem, jl);
  const int fh = half * 64;

  const bool valid = lane < m;
  const int j = valid ? (int)jl[lane] : 0;
  const float rx = bpos[j * 3 + 0] - qx;
  const float ry = bpos[j * 3 + 1] - qy;
  const float rz = bpos[j * 3 + 2] - qz;
  const float* urow = u + ((size_t)b * 2048 + j) * 128 + fh;

  float y1[64];
#pragma unroll
  for (int t = 0; t < 64; t += 4) {
    float4 v = *reinterpret_cast<const float4*>(urow + t);
    y1[t] = v.x; y1[t + 1] = v.y; y1[t + 2] = v.z; y1[t + 3] = v.w;
  }
#pragma unroll
  for (int t = 0; t < 64; ++t) {
    float a = fmaf(rx, w1r[0 * 128 + fh + t], y1[t]);
    a = fmaf(ry, w1r[1 * 128 + fh + t], a);
    a = fmaf(rz, w1r[2 * 128 + fh + t], a);
    y1[t] = fmaxf(a, 0.0f);
  }

  float* stgA = (float*)pairmem;           // half-0 wave's [32][65]
  float* stgB = (float*)(pairmem + 8704);  // half-1 wave's [32][65]
  float* stg_own = half ? stgB : stgA;     // == wmem
  float* orow = out + (size_t)qid * 128;
  const float NEG = -__builtin_inff();
#pragma unroll 1
  for (int cst = 0; cst < 128; cst += 32) {
#pragma unroll 1
    for (int g = 0; g < 32; ++g) {
      const float* wrow = w2t + (size_t)(cst + g) * 128 + fh;  // uniform -> s_load
      float a0 = 0.f, a1 = 0.f, a2 = 0.f, a3 = 0.f;
#pragma unroll
      for (int t = 0; t < 64; t += 4) {
        a0 = fmaf(y1[t], wrow[t], a0);
        a1 = fmaf(y1[t + 1], wrow[t + 1], a1);
        a2 = fmaf(y1[t + 2], wrow[t + 2], a2);
        a3 = fmaf(y1[t + 3], wrow[t + 3], a3);
      }
      float pc = (a0 + a1) + (a2 + a3);
      stg_own[g * 65 + lane] = valid ? pc : (half ? 0.0f : NEG);
    }
    __syncthreads();
    if (half == 0) {
      const int r = lane & 31, jb = (lane >> 5) * 32;
      float mx = NEG;
#pragma unroll
      for (int t = 0; t < 32; ++t)
        mx = fmaxf(mx, stgA[r * 65 + jb + t] + stgB[r * 65 + jb + t]);
      mx = fmaxf(mx, __shfl_xor(mx, 32));
      if (lane < 32) orow[cst + lane] = mx + b2[cst + lane];
    }
    __syncthreads();
  }
}

// ---------------- fused stage kernels: blocks 0..7 = FPS, rest = conv ----------------
__global__ __launch_bounds__(256, 2) void stage1_kernel(
    const float* __restrict__ coords, const float* __restrict__ feats,
    const float* __restrict__ w1, const float* __restrict__ b1,
    const float* __restrict__ w2t, const float* __restrict__ b2,
    float* __restrict__ out, int* __restrict__ fps_idx, float* __restrict__ fps_pos) {
  __shared__ __align__(16) char smem[36352];  // fps: <29KB; conv: 4 x 9088
  if (blockIdx.x < 8) {
    fps_body<4096, 2048>(coords, (int)blockIdx.x, fps_idx, fps_pos, smem);
  } else {
    int qid = __builtin_amdgcn_readfirstlane(((int)blockIdx.x - 8) * 4 + WID);
    conv1_body(coords, feats, w1, b1, w2t, b2, out, qid, smem + WID * 9088);
  }
}

__global__ __launch_bounds__(256, 2) void stage2_kernel(
    const float* __restrict__ p1, const float* __restrict__ u2,
    const float* __restrict__ w1r, const float* __restrict__ w2t,
    const float* __restrict__ b2, float* __restrict__ out,
    int* __restrict__ fps_idx) {
  __shared__ __align__(16) char smem[34816];  // fps: <8KB; conv: 4 x 8704
  if (blockIdx.x < 8) {
    fps_body<2048, 512>(p1, (int)blockIdx.x, fps_idx, nullptr, smem);
  } else {
    const int wid = WID;
    const int half = __builtin_amdgcn_readfirstlane(wid & 1);
    const int qid =
        __builtin_amdgcn_readfirstlane(((int)blockIdx.x - 8) * 2 + (wid >> 1));
    conv2_body(p1, u2, w1r, w2t, b2, out, qid, half, smem + wid * 8704,
               smem + (wid & ~1) * 8704);
  }
}

// ------- u2 = b1b + h1[i1] @ W1b_feat (layer-1 factoring for stage 2) -------
__global__ __launch_bounds__(128) void u2_kernel(const float* __restrict__ h1,
                                                 const int* __restrict__ i1,
                                                 const float* __restrict__ w1,
                                                 const float* __restrict__ b1,
                                                 float* __restrict__ u2) {
  int row = blockIdx.x;  // 16384
  int f = (int)threadIdx.x;
  int b = row >> 11;
  int src = i1[row];
  const float* x = h1 + ((size_t)b * 4096 + src) * 64;
  float acc = b1[f];
#pragma unroll
  for (int k = 0; k < 64; ++k) acc = fmaf(x[k], w1[k * 128 + f], acc);
  u2[(size_t)row * 128 + f] = acc;
}

__global__ __launch_bounds__(256) void transpose_kernel(const float* __restrict__ w2a,
                                                        const float* __restrict__ w2b,
                                                        float* __restrict__ w2ta,
                                                        float* __restrict__ w2tb) {
  int gtid = blockIdx.x * 256 + (int)threadIdx.x;
  int stride = gridDim.x * 256;
  for (int t = gtid; t < 64 * 64; t += stride) w2ta[(t & 63) * 64 + (t >> 6)] = w2a[t];
  for (int t = gtid; t < 128 * 128; t += stride) w2tb[(t & 127) * 128 + (t >> 7)] = w2b[t];
}

// ---------------- global max pool over i2 + final linear ----------------
__global__ __launch_bounds__(512) void pool_linear_kernel(
    const float* __restrict__ h2, const int* __restrict__ i2,
    const float* __restrict__ wl, const float* __restrict__ bl,
    float* __restrict__ out) {
  int b = blockIdx.x;
  int c = (int)threadIdx.x >> 7;
  int f = (int)threadIdx.x & 127;
  __shared__ float part[4][128];
  __shared__ float feat[128];
  float mx = -__builtin_inff();
  const int* idx = i2 + b * 512;
  for (int s = c * 128; s < c * 128 + 128; ++s) {
    int j = idx[s];
    mx = fmaxf(mx, h2[((size_t)b * 2048 + j) * 128 + f]);
  }
  part[c][f] = mx;
  __syncthreads();
  if (c == 0) {
    feat[f] = fmaxf(fmaxf(part[0][f], part[1][f]), fmaxf(part[2][f], part[3][f]));
  }
  __syncthreads();
  if (c == 0) {
    float acc = bl[f];
#pragma unroll
    for (int k = 0; k < 128; ++k) acc = fmaf(feat[k], wl[k * 128 + f], acc);
    out[b * 128 + f] = acc;
  }
}

extern "C" void kernel_launch(void* const* d_in, const int* in_sizes, int n_in,
                              void* d_out, int out_size, void* d_ws, size_t ws_size,
                              hipStream_t stream) {
  const float* feats = (const float*)d_in[0];   // [8,4096,6]
  const float* coords = (const float*)d_in[1];  // [8,4096,3]
  const float* W1a = (const float*)d_in[2];     // [9,64]
  const float* b1a = (const float*)d_in[3];
  const float* W2a = (const float*)d_in[4];     // [64,64]
  const float* b2a = (const float*)d_in[5];
  const float* W1b = (const float*)d_in[6];     // [67,128]
  const float* b1b = (const float*)d_in[7];
  const float* W2b = (const float*)d_in[8];     // [128,128]
  const float* b2b = (const float*)d_in[9];
  const float* Wl = (const float*)d_in[10];     // [128,128]
  const float* bl = (const float*)d_in[11];

  float* ws = (float*)d_ws;
  float* W2TA = ws;                  // 4096
  float* W2TB = W2TA + 4096;         // 16384
  float* H1 = W2TB + 16384;          // 8*4096*64  = 2097152
  float* U2 = H1 + 2097152;          // 8*2048*128 = 2097152
  float* H2 = U2 + 2097152;          // 8*2048*128 = 2097152
  float* P1 = H2 + 2097152;          // 8*2048*3   = 49152
  int* I1 = (int*)(P1 + 49152);      // 8*2048
  int* I2 = I1 + 16384;              // 8*512

  transpose_kernel<<<80, 256, 0, stream>>>(W2a, W2b, W2TA, W2TB);
  // stage 1: fps1 (blocks 0-7) || conv1 (8192 blocks x 4 queries)
  stage1_kernel<<<8 + 8192, 256, 0, stream>>>(coords, feats, W1a, b1a, W2TA, b2a, H1,
                                              I1, P1);
  u2_kernel<<<16384, 128, 0, stream>>>(H1, I1, W1b, b1b, U2);
  // stage 2: fps2 (blocks 0-7) || conv2 (8192 blocks x 2 queries x 2 waves)
  stage2_kernel<<<8 + 8192, 256, 0, stream>>>(P1, U2, W1b + 64 * 128, W2TB, b2b, H2, I2);
  pool_linear_kernel<<<8, 512, 0, stream>>>(H2, I2, Wl, bl, (float*)d_out);
}

// Round 7
// 2885.732 us; speedup vs baseline: 2.2050x; 1.0378x over previous
//
#include <hip/hip_runtime.h>
#include <stdint.h>

#define LANE ((int)(threadIdx.x & 63))
#define WID  ((int)(threadIdx.x >> 6))

__device__ __forceinline__ float exact_d2(float ax, float ay, float az,
                                          float bx, float by, float bz) {
  float dx = ax - bx, dy = ay - by, dz = az - bz;
  return __fadd_rn(__fadd_rn(__fmul_rn(dx, dx), __fmul_rn(dy, dy)), __fmul_rn(dz, dz));
}

__device__ __forceinline__ void lds_fence() {
  asm volatile("s_waitcnt lgkmcnt(0)" ::: "memory");
}

// Wave-wide max via DPP (VALU-latency, no LDS). ROW_SHR 1/2/4/8 accumulates row
// maxima into lanes 15/31/47/63 (data moves toward higher lanes; shifted-out
// sources yield `old` = -inf); row_bcast15 (rows 1,3) then row_bcast31 (rows 2,3)
// fold rows; lane 63 holds the full wave max. Matches LLVM AMDGPUAtomicOptimizer.
__device__ __forceinline__ float wave_max_dpp(float v) {
  const int NI = 0xff800000;  // -inf bits: identity
  int x = __float_as_int(v);
  x = __float_as_int(fmaxf(__int_as_float(x),
      __int_as_float(__builtin_amdgcn_update_dpp(NI, x, 0x111, 0xf, 0xf, false))));
  x = __float_as_int(fmaxf(__int_as_float(x),
      __int_as_float(__builtin_amdgcn_update_dpp(NI, x, 0x112, 0xf, 0xf, false))));
  x = __float_as_int(fmaxf(__int_as_float(x),
      __int_as_float(__builtin_amdgcn_update_dpp(NI, x, 0x114, 0xf, 0xf, false))));
  x = __float_as_int(fmaxf(__int_as_float(x),
      __int_as_float(__builtin_amdgcn_update_dpp(NI, x, 0x118, 0xf, 0xf, false))));
  x = __float_as_int(fmaxf(__int_as_float(x),
      __int_as_float(__builtin_amdgcn_update_dpp(NI, x, 0x142, 0xa, 0xf, false))));
  x = __float_as_int(fmaxf(__int_as_float(x),
      __int_as_float(__builtin_amdgcn_update_dpp(NI, x, 0x143, 0xc, 0xf, false))));
  return __int_as_float(__builtin_amdgcn_readlane(x, 63));
}

// ---------------- FPS body: 256 threads, one block per batch, 1 barrier/iter ------
// Per iter: dd update (winner coords carried in regs) -> DPP wave max -> ballot+ffs
// first-index winner lane -> masked rescan recovers bestk+coords (static cndmask
// chain) -> publish u64 key (dist bits, NPTS-1-idx) + coords to parity slot ->
// barrier -> single vectorized LDS round + cndmask merge tree over 4 wave keys.
template <int NPTS, int NSAMP>
__device__ void fps_body(const float* __restrict__ coords, int b,
                         int* __restrict__ out_idx, float* __restrict__ out_pos,
                         char* smem_raw) {
  constexpr int PT = NPTS / 256;
  uint64_t* swk = (uint64_t*)smem_raw;                         // [2][4] keys
  float4* swc = (float4*)(swk + 8);                            // [2][4] coords
  float* spos = (float*)(swc + 8);                             // [NSAMP*3]
  unsigned short* sidx = (unsigned short*)(spos + NSAMP * 3);  // [NSAMP]
  const float* pos = coords + (size_t)b * NPTS * 3;
  const int tid = (int)threadIdx.x;
  const int lane = LANE, wid = WID;

  __builtin_amdgcn_s_setprio(3);  // FPS is the serial critical path

  float px[PT], py[PT], pz[PT], dd[PT];
  const int i0 = tid * PT;
#pragma unroll
  for (int k = 0; k < PT; ++k) {
    px[k] = pos[(i0 + k) * 3 + 0];
    py[k] = pos[(i0 + k) * 3 + 1];
    pz[k] = pos[(i0 + k) * 3 + 2];
    dd[k] = __builtin_inff();
  }
  float fx = pos[0], fy = pos[1], fz = pos[2];
  if (tid == 0) {
    sidx[0] = 0;
    spos[0] = fx; spos[1] = fy; spos[2] = fz;
  }
  __syncthreads();

  for (int s = 1; s < NSAMP; ++s) {
    float lv = -__builtin_inff();
#pragma unroll
    for (int k = 0; k < PT; k += 2) {
      float d0 = exact_d2(px[k], py[k], pz[k], fx, fy, fz);
      dd[k] = fminf(dd[k], d0);
      float d1 = exact_d2(px[k + 1], py[k + 1], pz[k + 1], fx, fy, fz);
      dd[k + 1] = fminf(dd[k + 1], d1);
      lv = fmaxf(lv, fmaxf(dd[k], dd[k + 1]));  // fuses to v_max3
    }
    const float wv = wave_max_dpp(lv);
    const uint64_t mball = __ballot(lv == wv);
    const int wl = (int)__ffsll((unsigned long long)mball) - 1;  // lowest lane
    const int par = s & 1;
    if (lane == wl) {  // wave winner: recover first k + coords, publish pre-barrier
      int bestk = 0;
      float bx = px[0], by = py[0], bz = pz[0];
#pragma unroll
      for (int k = PT - 1; k >= 0; --k) {  // descending: smallest k wins
        if (dd[k] == wv) { bestk = k; bx = px[k]; by = py[k]; bz = pz[k]; }
      }
      swk[par * 4 + wid] =
          ((uint64_t)__float_as_uint(wv) << 32) | (unsigned)(NPTS - 1 - (i0 + bestk));
      swc[par * 4 + wid] = make_float4(bx, by, bz, 0.0f);
    }
    __syncthreads();
    // single LDS round: all keys + all coords issued together, one wait
    const uint64_t* kp = swk + par * 4;
    const uint64_t ka = kp[0], kb = kp[1], kc = kp[2], kd = kp[3];
    const float4 c0 = swc[par * 4 + 0], c1 = swc[par * 4 + 1];
    const float4 c2 = swc[par * 4 + 2], c3 = swc[par * 4 + 3];
    const bool s01 = kb > ka;
    const uint64_t k01 = s01 ? kb : ka;
    const bool s23 = kd > kc;
    const uint64_t k23 = s23 ? kd : kc;
    const bool sf = k23 > k01;
    const uint64_t kfin = sf ? k23 : k01;
    fx = sf ? (s23 ? c3.x : c2.x) : (s01 ? c1.x : c0.x);
    fy = sf ? (s23 ? c3.y : c2.y) : (s01 ? c1.y : c0.y);
    fz = sf ? (s23 ? c3.z : c2.z) : (s01 ? c1.z : c0.z);
    const unsigned widx = (unsigned)(NPTS - 1) - (unsigned)(kfin & 0xFFFFFFFFu);
    if (tid == 0) {
      sidx[s] = (unsigned short)widx;
      spos[s * 3 + 0] = fx; spos[s * 3 + 1] = fy; spos[s * 3 + 2] = fz;
    }
  }
  __syncthreads();
  for (int s = tid; s < NSAMP; s += 256) {
    out_idx[(size_t)b * NSAMP + s] = (int)sidx[s];
    if (out_pos) {
      out_pos[((size_t)b * NSAMP + s) * 3 + 0] = spos[s * 3 + 0];
      out_pos[((size_t)b * NSAMP + s) * 3 + 1] = spos[s * 3 + 1];
      out_pos[((size_t)b * NSAMP + s) * 3 + 2] = spos[s * 3 + 2];
    }
  }
}

// ---- exact neighbor selection: in-radius candidates, 64 nearest (d, then j) ----
template <int NPTS, int CAP>
__device__ __forceinline__ int select_neighbors(const float* __restrict__ bpos,
                                                float qx, float qy, float qz, float r2,
                                                char* wmem, unsigned* jl) {
  constexpr int SLOTS = CAP / 64;
  const int lane = LANE;
  uint64_t* list = (uint64_t*)wmem;
  const uint64_t ltmask = (1ull << lane) - 1ull;

  unsigned cnt = 0;
  for (int base = 0; base < NPTS; base += 64) {
    int j = base + lane;
    float d = exact_d2(bpos[j * 3], bpos[j * 3 + 1], bpos[j * 3 + 2], qx, qy, qz);
    bool pred = d < r2;
    uint64_t mask = __ballot(pred);
    if (pred) {
      unsigned p = cnt + (unsigned)__popcll(mask & ltmask);
      if (p < CAP) list[p] = ((uint64_t)__float_as_uint(d) << 32) | (unsigned)j;
    }
    cnt += (unsigned)__popcll(mask);
  }
  if (cnt > CAP) cnt = CAP;
  lds_fence();

  int m;
  if (cnt <= 64) {
    m = (int)cnt;
    jl[lane] = (lane < m) ? (unsigned)list[lane] : 0u;
  } else {
    m = 64;
    uint64_t e[SLOTS];
#pragma unroll
    for (int si = 0; si < SLOTS; ++si) {
      int p = lane + 64 * si;
      e[si] = (p < (int)cnt) ? list[p] : ~0ull;
    }
    // binary search for d* = 64th smallest distance bit-pattern
    unsigned lo = 0, hi = 0x3F800000u;
    while (lo < hi) {
      unsigned mid = (lo + hi) >> 1;
      unsigned c = 0;
#pragma unroll
      for (int si = 0; si < SLOTS; ++si)
        c += (unsigned)__popcll(__ballot((unsigned)(e[si] >> 32) <= mid));
      if (c >= 64u) hi = mid; else lo = mid + 1;
    }
    const unsigned dstar = lo;
    unsigned nlt = 0, nt = 0;
#pragma unroll
    for (int si = 0; si < SLOTS; ++si) {
      unsigned hb = (unsigned)(e[si] >> 32);
      nlt += (unsigned)__popcll(__ballot(hb < dstar));
      nt += (unsigned)__popcll(__ballot(hb == dstar));
    }
    const unsigned need = 64u - nlt;
    unsigned jsel = 0xFFFFFFFFu;
    if (nt != need) {  // distance tie at the cut -> keep `need` smallest j
      unsigned jlo = 0, jhi = (unsigned)NPTS - 1;
      while (jlo < jhi) {
        unsigned jmid = (jlo + jhi) >> 1;
        unsigned c = 0;
#pragma unroll
        for (int si = 0; si < SLOTS; ++si)
          c += (unsigned)__popcll(__ballot(
              ((unsigned)(e[si] >> 32) == dstar) && ((unsigned)e[si] <= jmid)));
        if (c >= need) jhi = jmid; else jlo = jmid + 1;
      }
      jsel = jlo;
    }
    unsigned c2 = 0;
#pragma unroll
    for (int si = 0; si < SLOTS; ++si) {
      unsigned hb = (unsigned)(e[si] >> 32), jj = (unsigned)e[si];
      bool p = (hb < dstar) || ((hb == dstar) && (jj <= jsel));
      uint64_t mask = __ballot(p);
      if (p) jl[c2 + (unsigned)__popcll(mask & ltmask)] = jj;
      c2 += (unsigned)__popcll(mask);
    }
  }
  lds_fence();
  return m;
}

// ---------------- conv1: H=64, lane = neighbor, y1[64] in regs ----------------
__device__ void conv1_body(const float* __restrict__ pos, const float* __restrict__ feats,
                           const float* __restrict__ w1, const float* __restrict__ b1,
                           const float* __restrict__ w2t, const float* __restrict__ b2,
                           float* __restrict__ out, int qid, char* wmem) {
  const int lane = LANE;
  const int b = qid >> 12, qi = qid & 4095;
  const float* bpos = pos + (size_t)b * 4096 * 3;
  const float qx = bpos[qi * 3 + 0], qy = bpos[qi * 3 + 1], qz = bpos[qi * 3 + 2];
  unsigned* jl = (unsigned*)(wmem + 8320);
  const int m = select_neighbors<4096, 512>(bpos, qx, qy, qz, 0.04f, wmem, jl);

  const bool valid = lane < m;
  const int j = valid ? (int)jl[lane] : 0;
  const float rx = bpos[j * 3 + 0] - qx;
  const float ry = bpos[j * 3 + 1] - qy;
  const float rz = bpos[j * 3 + 2] - qz;
  const float* xr = feats + ((size_t)b * 4096 + j) * 6;
  const float x0 = xr[0], x1 = xr[1], x2 = xr[2], x3 = xr[3], x4 = xr[4], x5 = xr[5];
  const float* w1r = w1 + 6 * 64;

  float y1[64];
#pragma unroll
  for (int f = 0; f < 64; ++f) {
    float a = b1[f];
    a = fmaf(x0, w1[0 * 64 + f], a);
    a = fmaf(x1, w1[1 * 64 + f], a);
    a = fmaf(x2, w1[2 * 64 + f], a);
    a = fmaf(x3, w1[3 * 64 + f], a);
    a = fmaf(x4, w1[4 * 64 + f], a);
    a = fmaf(x5, w1[5 * 64 + f], a);
    a = fmaf(rx, w1r[0 * 64 + f], a);
    a = fmaf(ry, w1r[1 * 64 + f], a);
    a = fmaf(rz, w1r[2 * 64 + f], a);
    y1[f] = fmaxf(a, 0.0f);
  }

  float* stg = (float*)wmem;  // [32][65], reuses candidate area
  float* orow = out + (size_t)qid * 64;
  const float NEG = -__builtin_inff();
#pragma unroll 1
  for (int cst = 0; cst < 64; cst += 32) {
    lds_fence();
#pragma unroll 1
    for (int g = 0; g < 32; ++g) {
      const float* wrow = w2t + (size_t)(cst + g) * 64;  // uniform -> s_load
      float a0 = 0.f, a1 = 0.f, a2 = 0.f, a3 = 0.f;
#pragma unroll
      for (int f = 0; f < 64; f += 4) {
        a0 = fmaf(y1[f], wrow[f], a0);
        a1 = fmaf(y1[f + 1], wrow[f + 1], a1);
        a2 = fmaf(y1[f + 2], wrow[f + 2], a2);
        a3 = fmaf(y1[f + 3], wrow[f + 3], a3);
      }
      float acc = b2[cst + g] + ((a0 + a1) + (a2 + a3));
      stg[g * 65 + lane] = valid ? acc : NEG;
    }
    lds_fence();
    const int r = lane & 31, jb = lane & 32;
    float mx = NEG;
#pragma unroll
    for (int t = 0; t < 32; ++t) mx = fmaxf(mx, stg[r * 65 + jb + t]);
    mx = fmaxf(mx, __shfl_xor(mx, 32));
    if (lane < 32) orow[cst + lane] = mx;
  }
}

// ------- conv2: H=128, TWO waves per query (wave-uniform feature half) -------
__device__ void conv2_body(const float* __restrict__ pos, const float* __restrict__ u,
                           const float* __restrict__ w1r, const float* __restrict__ w2t,
                           const float* __restrict__ b2, float* __restrict__ out,
                           int qid, int half, char* wmem, char* pairmem) {
  const int lane = LANE;
  const int b = qid >> 11, qi = qid & 2047;
  const float* bpos = pos + (size_t)b * 2048 * 3;
  const float qx = bpos[qi * 3 + 0], qy = bpos[qi * 3 + 1], qz = bpos[qi * 3 + 2];
  unsigned* jl = (unsigned*)(wmem + 8320);
  const int m = select_neighbors<2048, 1024>(bpos, qx, qy, qz, 0.16f, wmem, jl);
  const int fh = half * 64;

  const bool valid = lane < m;
  const int j = valid ? (int)jl[lane] : 0;
  const float rx = bpos[j * 3 + 0] - qx;
  const float ry = bpos[j * 3 + 1] - qy;
  const float rz = bpos[j * 3 + 2] - qz;
  const float* urow = u + ((size_t)b * 2048 + j) * 128 + fh;

  float y1[64];
#pragma unroll
  for (int t = 0; t < 64; t += 4) {
    float4 v = *reinterpret_cast<const float4*>(urow + t);
    y1[t] = v.x; y1[t + 1] = v.y; y1[t + 2] = v.z; y1[t + 3] = v.w;
  }
#pragma unroll
  for (int t = 0; t < 64; ++t) {
    float a = fmaf(rx, w1r[0 * 128 + fh + t], y1[t]);
    a = fmaf(ry, w1r[1 * 128 + fh + t], a);
    a = fmaf(rz, w1r[2 * 128 + fh + t], a);
    y1[t] = fmaxf(a, 0.0f);
  }

  float* stgA = (float*)pairmem;           // half-0 wave's [32][65]
  float* stgB = (float*)(pairmem + 8704);  // half-1 wave's [32][65]
  float* stg_own = half ? stgB : stgA;     // == wmem
  float* orow = out + (size_t)qid * 128;
  const float NEG = -__builtin_inff();
#pragma unroll 1
  for (int cst = 0; cst < 128; cst += 32) {
#pragma unroll 1
    for (int g = 0; g < 32; ++g) {
      const float* wrow = w2t + (size_t)(cst + g) * 128 + fh;  // uniform -> s_load
      float a0 = 0.f, a1 = 0.f, a2 = 0.f, a3 = 0.f;
#pragma unroll
      for (int t = 0; t < 64; t += 4) {
        a0 = fmaf(y1[t], wrow[t], a0);
        a1 = fmaf(y1[t + 1], wrow[t + 1], a1);
        a2 = fmaf(y1[t + 2], wrow[t + 2], a2);
        a3 = fmaf(y1[t + 3], wrow[t + 3], a3);
      }
      float pc = (a0 + a1) + (a2 + a3);
      stg_own[g * 65 + lane] = valid ? pc : (half ? 0.0f : NEG);
    }
    __syncthreads();
    if (half == 0) {
      const int r = lane & 31, jb = (lane >> 5) * 32;
      float mx = NEG;
#pragma unroll
      for (int t = 0; t < 32; ++t)
        mx = fmaxf(mx, stgA[r * 65 + jb + t] + stgB[r * 65 + jb + t]);
      mx = fmaxf(mx, __shfl_xor(mx, 32));
      if (lane < 32) orow[cst + lane] = mx + b2[cst + lane];
    }
    __syncthreads();
  }
}

// ---------------- fused stage kernels: blocks 0..7 = FPS, rest = conv ----------------
__global__ __launch_bounds__(256, 2) void stage1_kernel(
    const float* __restrict__ coords, const float* __restrict__ feats,
    const float* __restrict__ w1, const float* __restrict__ b1,
    const float* __restrict__ w2t, const float* __restrict__ b2,
    float* __restrict__ out, int* __restrict__ fps_idx, float* __restrict__ fps_pos) {
  __shared__ __align__(16) char smem[36352];  // fps: <29KB; conv: 4 x 9088
  if (blockIdx.x < 8) {
    fps_body<4096, 2048>(coords, (int)blockIdx.x, fps_idx, fps_pos, smem);
  } else {
    int qid = __builtin_amdgcn_readfirstlane(((int)blockIdx.x - 8) * 4 + WID);
    conv1_body(coords, feats, w1, b1, w2t, b2, out, qid, smem + WID * 9088);
  }
}

__global__ __launch_bounds__(256, 2) void stage2_kernel(
    const float* __restrict__ p1, const float* __restrict__ u2,
    const float* __restrict__ w1r, const float* __restrict__ w2t,
    const float* __restrict__ b2, float* __restrict__ out,
    int* __restrict__ fps_idx) {
  __shared__ __align__(16) char smem[34816];  // fps: <8KB; conv: 4 x 8704
  if (blockIdx.x < 8) {
    fps_body<2048, 512>(p1, (int)blockIdx.x, fps_idx, nullptr, smem);
  } else {
    const int wid = WID;
    const int half = __builtin_amdgcn_readfirstlane(wid & 1);
    const int qid =
        __builtin_amdgcn_readfirstlane(((int)blockIdx.x - 8) * 2 + (wid >> 1));
    conv2_body(p1, u2, w1r, w2t, b2, out, qid, half, smem + wid * 8704,
               smem + (wid & ~1) * 8704);
  }
}

// ------- u2 = b1b + h1[i1] @ W1b_feat (layer-1 factoring for stage 2) -------
__global__ __launch_bounds__(128) void u2_kernel(const float* __restrict__ h1,
                                                 const int* __restrict__ i1,
                                                 const float* __restrict__ w1,
                                                 const float* __restrict__ b1,
                                                 float* __restrict__ u2) {
  int row = blockIdx.x;  // 16384
  int f = (int)threadIdx.x;
  int b = row >> 11;
  int src = i1[row];
  const float* x = h1 + ((size_t)b * 4096 + src) * 64;
  float acc = b1[f];
#pragma unroll
  for (int k = 0; k < 64; ++k) acc = fmaf(x[k], w1[k * 128 + f], acc);
  u2[(size_t)row * 128 + f] = acc;
}

__global__ __launch_bounds__(256) void transpose_kernel(const float* __restrict__ w2a,
                                                        const float* __restrict__ w2b,
                                                        float* __restrict__ w2ta,
                                                        float* __restrict__ w2tb) {
  int gtid = blockIdx.x * 256 + (int)threadIdx.x;
  int stride = gridDim.x * 256;
  for (int t = gtid; t < 64 * 64; t += stride) w2ta[(t & 63) * 64 + (t >> 6)] = w2a[t];
  for (int t = gtid; t < 128 * 128; t += stride) w2tb[(t & 127) * 128 + (t >> 7)] = w2b[t];
}

// ---------------- global max pool over i2 + final linear ----------------
__global__ __launch_bounds__(512) void pool_linear_kernel(
    const float* __restrict__ h2, const int* __restrict__ i2,
    const float* __restrict__ wl, const float* __restrict__ bl,
    float* __restrict__ out) {
  int b = blockIdx.x;
  int c = (int)threadIdx.x >> 7;
  int f = (int)threadIdx.x & 127;
  __shared__ float part[4][128];
  __shared__ float feat[128];
  float mx = -__builtin_inff();
  const int* idx = i2 + b * 512;
  for (int s = c * 128; s < c * 128 + 128; ++s) {
    int j = idx[s];
    mx = fmaxf(mx, h2[((size_t)b * 2048 + j) * 128 + f]);
  }
  part[c][f] = mx;
  __syncthreads();
  if (c == 0) {
    feat[f] = fmaxf(fmaxf(part[0][f], part[1][f]), fmaxf(part[2][f], part[3][f]));
  }
  __syncthreads();
  if (c == 0) {
    float acc = bl[f];
#pragma unroll
    for (int k = 0; k < 128; ++k) acc = fmaf(feat[k], wl[k * 128 + f], acc);
    out[b * 128 + f] = acc;
  }
}

extern "C" void kernel_launch(void* const* d_in, const int* in_sizes, int n_in,
                              void* d_out, int out_size, void* d_ws, size_t ws_size,
                              hipStream_t stream) {
  const float* feats = (const float*)d_in[0];   // [8,4096,6]
  const float* coords = (const float*)d_in[1];  // [8,4096,3]
  const float* W1a = (const float*)d_in[2];     // [9,64]
  const float* b1a = (const float*)d_in[3];
  const float* W2a = (const float*)d_in[4];     // [64,64]
  const float* b2a = (const float*)d_in[5];
  const float* W1b = (const float*)d_in[6];     // [67,128]
  const float* b1b = (const float*)d_in[7];
  const float* W2b = (const float*)d_in[8];     // [128,128]
  const float* b2b = (const float*)d_in[9];
  const float* Wl = (const float*)d_in[10];     // [128,128]
  const float* bl = (const float*)d_in[11];

  float* ws = (float*)d_ws;
  float* W2TA = ws;                  // 4096
  float* W2TB = W2TA + 4096;         // 16384
  float* H1 = W2TB + 16384;          // 8*4096*64  = 2097152
  float* U2 = H1 + 2097152;          // 8*2048*128 = 2097152
  float* H2 = U2 + 2097152;          // 8*2048*128 = 2097152
  float* P1 = H2 + 2097152;          // 8*2048*3   = 49152
  int* I1 = (int*)(P1 + 49152);      // 8*2048
  int* I2 = I1 + 16384;              // 8*512

  transpose_kernel<<<80, 256, 0, stream>>>(W2a, W2b, W2TA, W2TB);
  // stage 1: fps1 (blocks 0-7) || conv1 (8192 blocks x 4 queries)
  stage1_kernel<<<8 + 8192, 256, 0, stream>>>(coords, feats, W1a, b1a, W2TA, b2a, H1,
                                              I1, P1);
  u2_kernel<<<16384, 128, 0, stream>>>(H1, I1, W1b, b1b, U2);
  // stage 2: fps2 (blocks 0-7) || conv2 (8192 blocks x 2 queries x 2 waves)
  stage2_kernel<<<8 + 8192, 256, 0, stream>>>(P1, U2, W1b + 64 * 128, W2TB, b2b, H2, I2);
  pool_linear_kernel<<<8, 512, 0, stream>>>(H2, I2, Wl, bl, (float*)d_out);
}

// Round 8
// 2288.362 us; speedup vs baseline: 2.7806x; 1.2610x over previous
//
#include <hip/hip_runtime.h>
#include <stdint.h>

#define LANE ((int)(threadIdx.x & 63))
#define WID  ((int)(threadIdx.x >> 6))

__device__ __forceinline__ float exact_d2(float ax, float ay, float az,
                                          float bx, float by, float bz) {
  float dx = ax - bx, dy = ay - by, dz = az - bz;
  return __fadd_rn(__fadd_rn(__fmul_rn(dx, dx), __fmul_rn(dy, dy)), __fmul_rn(dz, dz));
}

__device__ __forceinline__ void lds_fence() {
  asm volatile("s_waitcnt lgkmcnt(0)" ::: "memory");
}

// Wave-wide max via DPP. ROW_SHR 1/2/4/8 accumulates row maxima into lanes
// 15/31/47/63; row_bcast15 (rows 1,3) then row_bcast31 (rows 2,3) fold rows;
// lane 63 holds the full wave max. (R7-verified.)
__device__ __forceinline__ float wave_max_dpp(float v) {
  const int NI = 0xff800000;  // -inf bits: identity
  int x = __float_as_int(v);
  x = __float_as_int(fmaxf(__int_as_float(x),
      __int_as_float(__builtin_amdgcn_update_dpp(NI, x, 0x111, 0xf, 0xf, false))));
  x = __float_as_int(fmaxf(__int_as_float(x),
      __int_as_float(__builtin_amdgcn_update_dpp(NI, x, 0x112, 0xf, 0xf, false))));
  x = __float_as_int(fmaxf(__int_as_float(x),
      __int_as_float(__builtin_amdgcn_update_dpp(NI, x, 0x114, 0xf, 0xf, false))));
  x = __float_as_int(fmaxf(__int_as_float(x),
      __int_as_float(__builtin_amdgcn_update_dpp(NI, x, 0x118, 0xf, 0xf, false))));
  x = __float_as_int(fmaxf(__int_as_float(x),
      __int_as_float(__builtin_amdgcn_update_dpp(NI, x, 0x142, 0xa, 0xf, false))));
  x = __float_as_int(fmaxf(__int_as_float(x),
      __int_as_float(__builtin_amdgcn_update_dpp(NI, x, 0x143, 0xc, 0xf, false))));
  return __int_as_float(__builtin_amdgcn_readlane(x, 63));
}

// ---------------- FPS body: symmetric waves, keys-only LDS round ----------------
// Per iter: dd update with inline (lv,li) tracking -> DPP wave max -> ballot picks
// lowest winning lane (= smallest index) -> winner lane publishes u64 key (dist
// bits, NPTS-1-idx) to parity slot -> barrier -> all read 4 keys, 3-compare merge
// -> widx -> winner coords via 3 broadcast LDS reads from the coords table ->
// tid0 logs idx/pos straight to global (stores retire off the critical path).
template <int NPTS, int NSAMP>
__device__ void fps_body(const float* __restrict__ coords, int b,
                         int* __restrict__ out_idx, float* __restrict__ out_pos,
                         char* smem_raw) {
  constexpr int PT = NPTS / 256;
  float* sx = (float*)smem_raw;                 // [NPTS]
  float* sy = sx + NPTS;                        // [NPTS]
  float* sz = sy + NPTS;                        // [NPTS]
  uint64_t* swk = (uint64_t*)(sz + NPTS);       // [2][4] keys
  const float* pos = coords + (size_t)b * NPTS * 3;
  const int tid = (int)threadIdx.x;
  const int lane = LANE, wid = WID;

  __builtin_amdgcn_s_setprio(3);  // FPS is the serial critical path

  float px[PT], py[PT], pz[PT], dd[PT];
  const int i0 = tid * PT;
#pragma unroll
  for (int k = 0; k < PT; ++k) {
    px[k] = pos[(i0 + k) * 3 + 0];
    py[k] = pos[(i0 + k) * 3 + 1];
    pz[k] = pos[(i0 + k) * 3 + 2];
    sx[i0 + k] = px[k]; sy[i0 + k] = py[k]; sz[i0 + k] = pz[k];
    dd[k] = __builtin_inff();
  }
  float fx = pos[0], fy = pos[1], fz = pos[2];
  if (tid == 0) {
    out_idx[(size_t)b * NSAMP] = 0;
    if (out_pos) {
      out_pos[(size_t)b * NSAMP * 3 + 0] = fx;
      out_pos[(size_t)b * NSAMP * 3 + 1] = fy;
      out_pos[(size_t)b * NSAMP * 3 + 2] = fz;
    }
  }
  __syncthreads();

  for (int s = 1; s < NSAMP; ++s) {
    float lv = -__builtin_inff();
    int li = 0;
#pragma unroll
    for (int k = 0; k < PT; ++k) {
      float d = exact_d2(px[k], py[k], pz[k], fx, fy, fz);
      float nd = fminf(dd[k], d);
      dd[k] = nd;
      bool gt = nd > lv;  // strict >: first k within thread wins ties
      lv = gt ? nd : lv;
      li = gt ? k : li;
    }
    const float wv = wave_max_dpp(lv);
    const uint64_t mball = __ballot(lv == wv);
    const int wl = (int)__ffsll((unsigned long long)mball) - 1;  // lowest lane
    const int par = s & 1;
    if (lane == wl) {  // symmetric cost: single ds_write_b64, no rescan
      swk[par * 4 + wid] =
          ((uint64_t)__float_as_uint(wv) << 32) | (unsigned)(NPTS - 1 - (i0 + li));
    }
    __syncthreads();
    const uint64_t* kp = swk + par * 4;
    const uint64_t ka = kp[0], kb = kp[1], kc = kp[2], kd = kp[3];
    const uint64_t k01 = kb > ka ? kb : ka;
    const uint64_t k23 = kd > kc ? kd : kc;
    const uint64_t kfin = k23 > k01 ? k23 : k01;
    const int widx = (NPTS - 1) - (int)(unsigned)(kfin & 0xFFFFFFFFu);
    fx = sx[widx]; fy = sy[widx]; fz = sz[widx];  // broadcast reads, bit-exact copies
    if (tid == 0) {
      out_idx[(size_t)b * NSAMP + s] = widx;
      if (out_pos) {
        out_pos[((size_t)b * NSAMP + s) * 3 + 0] = fx;
        out_pos[((size_t)b * NSAMP + s) * 3 + 1] = fy;
        out_pos[((size_t)b * NSAMP + s) * 3 + 2] = fz;
      }
    }
  }
}

// ---- exact neighbor selection: in-radius candidates, 64 nearest (d, then j) ----
template <int NPTS, int CAP>
__device__ __forceinline__ int select_neighbors(const float* __restrict__ bpos,
                                                float qx, float qy, float qz, float r2,
                                                char* wmem, unsigned* jl) {
  constexpr int SLOTS = CAP / 64;
  const int lane = LANE;
  uint64_t* list = (uint64_t*)wmem;
  const uint64_t ltmask = (1ull << lane) - 1ull;

  unsigned cnt = 0;
  for (int base = 0; base < NPTS; base += 64) {
    int j = base + lane;
    float d = exact_d2(bpos[j * 3], bpos[j * 3 + 1], bpos[j * 3 + 2], qx, qy, qz);
    bool pred = d < r2;
    uint64_t mask = __ballot(pred);
    if (pred) {
      unsigned p = cnt + (unsigned)__popcll(mask & ltmask);
      if (p < CAP) list[p] = ((uint64_t)__float_as_uint(d) << 32) | (unsigned)j;
    }
    cnt += (unsigned)__popcll(mask);
  }
  if (cnt > CAP) cnt = CAP;
  lds_fence();

  int m;
  if (cnt <= 64) {
    m = (int)cnt;
    jl[lane] = (lane < m) ? (unsigned)list[lane] : 0u;
  } else {
    m = 64;
    uint64_t e[SLOTS];
#pragma unroll
    for (int si = 0; si < SLOTS; ++si) {
      int p = lane + 64 * si;
      e[si] = (p < (int)cnt) ? list[p] : ~0ull;
    }
    // binary search for d* = 64th smallest distance bit-pattern
    unsigned lo = 0, hi = 0x3F800000u;
    while (lo < hi) {
      unsigned mid = (lo + hi) >> 1;
      unsigned c = 0;
#pragma unroll
      for (int si = 0; si < SLOTS; ++si)
        c += (unsigned)__popcll(__ballot((unsigned)(e[si] >> 32) <= mid));
      if (c >= 64u) hi = mid; else lo = mid + 1;
    }
    const unsigned dstar = lo;
    unsigned nlt = 0, nt = 0;
#pragma unroll
    for (int si = 0; si < SLOTS; ++si) {
      unsigned hb = (unsigned)(e[si] >> 32);
      nlt += (unsigned)__popcll(__ballot(hb < dstar));
      nt += (unsigned)__popcll(__ballot(hb == dstar));
    }
    const unsigned need = 64u - nlt;
    unsigned jsel = 0xFFFFFFFFu;
    if (nt != need) {  // distance tie at the cut -> keep `need` smallest j
      unsigned jlo = 0, jhi = (unsigned)NPTS - 1;
      while (jlo < jhi) {
        unsigned jmid = (jlo + jhi) >> 1;
        unsigned c = 0;
#pragma unroll
        for (int si = 0; si < SLOTS; ++si)
          c += (unsigned)__popcll(__ballot(
              ((unsigned)(e[si] >> 32) == dstar) && ((unsigned)e[si] <= jmid)));
        if (c >= need) jhi = jmid; else jlo = jmid + 1;
      }
      jsel = jlo;
    }
    unsigned c2 = 0;
#pragma unroll
    for (int si = 0; si < SLOTS; ++si) {
      unsigned hb = (unsigned)(e[si] >> 32), jj = (unsigned)e[si];
      bool p = (hb < dstar) || ((hb == dstar) && (jj <= jsel));
      uint64_t mask = __ballot(p);
      if (p) jl[c2 + (unsigned)__popcll(mask & ltmask)] = jj;
      c2 += (unsigned)__popcll(mask);
    }
  }
  lds_fence();
  return m;
}

// ---------------- conv1: H=64, lane = neighbor, y1[64] in regs ----------------
__device__ void conv1_body(const float* __restrict__ pos, const float* __restrict__ feats,
                           const float* __restrict__ w1, const float* __restrict__ b1,
                           const float* __restrict__ w2t, const float* __restrict__ b2,
                           float* __restrict__ out, int qid, char* wmem) {
  const int lane = LANE;
  const int b = qid >> 12, qi = qid & 4095;
  const float* bpos = pos + (size_t)b * 4096 * 3;
  const float qx = bpos[qi * 3 + 0], qy = bpos[qi * 3 + 1], qz = bpos[qi * 3 + 2];
  unsigned* jl = (unsigned*)(wmem + 8320);
  const int m = select_neighbors<4096, 512>(bpos, qx, qy, qz, 0.04f, wmem, jl);

  const bool valid = lane < m;
  const int j = valid ? (int)jl[lane] : 0;
  const float rx = bpos[j * 3 + 0] - qx;
  const float ry = bpos[j * 3 + 1] - qy;
  const float rz = bpos[j * 3 + 2] - qz;
  const float* xr = feats + ((size_t)b * 4096 + j) * 6;
  const float x0 = xr[0], x1 = xr[1], x2 = xr[2], x3 = xr[3], x4 = xr[4], x5 = xr[5];
  const float* w1r = w1 + 6 * 64;

  float y1[64];
#pragma unroll
  for (int f = 0; f < 64; ++f) {
    float a = b1[f];
    a = fmaf(x0, w1[0 * 64 + f], a);
    a = fmaf(x1, w1[1 * 64 + f], a);
    a = fmaf(x2, w1[2 * 64 + f], a);
    a = fmaf(x3, w1[3 * 64 + f], a);
    a = fmaf(x4, w1[4 * 64 + f], a);
    a = fmaf(x5, w1[5 * 64 + f], a);
    a = fmaf(rx, w1r[0 * 64 + f], a);
    a = fmaf(ry, w1r[1 * 64 + f], a);
    a = fmaf(rz, w1r[2 * 64 + f], a);
    y1[f] = fmaxf(a, 0.0f);
  }

  float* stg = (float*)wmem;  // [32][65], reuses candidate area
  float* orow = out + (size_t)qid * 64;
  const float NEG = -__builtin_inff();
#pragma unroll 1
  for (int cst = 0; cst < 64; cst += 32) {
    lds_fence();
#pragma unroll 1
    for (int g = 0; g < 32; ++g) {
      const float* wrow = w2t + (size_t)(cst + g) * 64;  // uniform -> s_load
      float a0 = 0.f, a1 = 0.f, a2 = 0.f, a3 = 0.f;
#pragma unroll
      for (int f = 0; f < 64; f += 4) {
        a0 = fmaf(y1[f], wrow[f], a0);
        a1 = fmaf(y1[f + 1], wrow[f + 1], a1);
        a2 = fmaf(y1[f + 2], wrow[f + 2], a2);
        a3 = fmaf(y1[f + 3], wrow[f + 3], a3);
      }
      float acc = b2[cst + g] + ((a0 + a1) + (a2 + a3));
      stg[g * 65 + lane] = valid ? acc : NEG;
    }
    lds_fence();
    const int r = lane & 31, jb = lane & 32;
    float mx = NEG;
#pragma unroll
    for (int t = 0; t < 32; ++t) mx = fmaxf(mx, stg[r * 65 + jb + t]);
    mx = fmaxf(mx, __shfl_xor(mx, 32));
    if (lane < 32) orow[cst + lane] = mx;
  }
}

// ------- conv2: H=128, TWO waves per query (wave-uniform feature half) -------
__device__ void conv2_body(const float* __restrict__ pos, const float* __restrict__ u,
                           const float* __restrict__ w1r, const float* __restrict__ w2t,
                           const float* __restrict__ b2, float* __restrict__ out,
                           int qid, int half, char* wmem, char* pairmem) {
  const int lane = LANE;
  const int b = qid >> 11, qi = qid & 2047;
  const float* bpos = pos + (size_t)b * 2048 * 3;
  const float qx = bpos[qi * 3 + 0], qy = bpos[qi * 3 + 1], qz = bpos[qi * 3 + 2];
  unsigned* jl = (unsigned*)(wmem + 8320);
  const int m = select_neighbors<2048, 1024>(bpos, qx, qy, qz, 0.16f, wmem, jl);
  const int fh = half * 64;

  const bool valid = lane < m;
  const int j = valid ? (int)jl[lane] : 0;
  const float rx = bpos[j * 3 + 0] - qx;
  const float ry = bpos[j * 3 + 1] - qy;
  const float rz = bpos[j * 3 + 2] - qz;
  const float* urow = u + ((size_t)b * 2048 + j) * 128 + fh;

  float y1[64];
#pragma unroll
  for (int t = 0; t < 64; t += 4) {
    float4 v = *reinterpret_cast<const float4*>(urow + t);
    y1[t] = v.x; y1[t + 1] = v.y; y1[t + 2] = v.z; y1[t + 3] = v.w;
  }
#pragma unroll
  for (int t = 0; t < 64; ++t) {
    float a = fmaf(rx, w1r[0 * 128 + fh + t], y1[t]);
    a = fmaf(ry, w1r[1 * 128 + fh + t], a);
    a = fmaf(rz, w1r[2 * 128 + fh + t], a);
    y1[t] = fmaxf(a, 0.0f);
  }

  float* stgA = (float*)pairmem;           // half-0 wave's [32][65]
  float* stgB = (float*)(pairmem + 8704);  // half-1 wave's [32][65]
  float* stg_own = half ? stgB : stgA;     // == wmem
  float* orow = out + (size_t)qid * 128;
  const float NEG = -__builtin_inff();
#pragma unroll 1
  for (int cst = 0; cst < 128; cst += 32) {
#pragma unroll 1
    for (int g = 0; g < 32; ++g) {
      const float* wrow = w2t + (size_t)(cst + g) * 128 + fh;  // uniform -> s_load
      float a0 = 0.f, a1 = 0.f, a2 = 0.f, a3 = 0.f;
#pragma unroll
      for (int t = 0; t < 64; t += 4) {
        a0 = fmaf(y1[t], wrow[t], a0);
        a1 = fmaf(y1[t + 1], wrow[t + 1], a1);
        a2 = fmaf(y1[t + 2], wrow[t + 2], a2);
        a3 = fmaf(y1[t + 3], wrow[t + 3], a3);
      }
      float pc = (a0 + a1) + (a2 + a3);
      stg_own[g * 65 + lane] = valid ? pc : (half ? 0.0f : NEG);
    }
    __syncthreads();
    if (half == 0) {
      const int r = lane & 31, jb = (lane >> 5) * 32;
      float mx = NEG;
#pragma unroll
      for (int t = 0; t < 32; ++t)
        mx = fmaxf(mx, stgA[r * 65 + jb + t] + stgB[r * 65 + jb + t]);
      mx = fmaxf(mx, __shfl_xor(mx, 32));
      if (lane < 32) orow[cst + lane] = mx + b2[cst + lane];
    }
    __syncthreads();
  }
}

// ---------------- fused stage kernels: blocks 0..7 = FPS, rest = conv ----------------
__global__ __launch_bounds__(256, 2) void stage1_kernel(
    const float* __restrict__ coords, const float* __restrict__ feats,
    const float* __restrict__ w1, const float* __restrict__ b1,
    const float* __restrict__ w2t, const float* __restrict__ b2,
    float* __restrict__ out, int* __restrict__ fps_idx, float* __restrict__ fps_pos) {
  __shared__ __align__(16) char smem[49216];  // fps: 48KB table + keys; conv: 4 x 9088
  if (blockIdx.x < 8) {
    fps_body<4096, 2048>(coords, (int)blockIdx.x, fps_idx, fps_pos, smem);
  } else {
    int qid = __builtin_amdgcn_readfirstlane(((int)blockIdx.x - 8) * 4 + WID);
    conv1_body(coords, feats, w1, b1, w2t, b2, out, qid, smem + WID * 9088);
  }
}

__global__ __launch_bounds__(256, 2) void stage2_kernel(
    const float* __restrict__ p1, const float* __restrict__ u2,
    const float* __restrict__ w1r, const float* __restrict__ w2t,
    const float* __restrict__ b2, float* __restrict__ out,
    int* __restrict__ fps_idx) {
  __shared__ __align__(16) char smem[34816];  // fps: 24KB+keys; conv: 4 x 8704
  if (blockIdx.x < 8) {
    fps_body<2048, 512>(p1, (int)blockIdx.x, fps_idx, nullptr, smem);
  } else {
    const int wid = WID;
    const int half = __builtin_amdgcn_readfirstlane(wid & 1);
    const int qid =
        __builtin_amdgcn_readfirstlane(((int)blockIdx.x - 8) * 2 + (wid >> 1));
    conv2_body(p1, u2, w1r, w2t, b2, out, qid, half, smem + wid * 8704,
               smem + (wid & ~1) * 8704);
  }
}

// ------- u2 = b1b + h1[i1] @ W1b_feat (layer-1 factoring for stage 2) -------
__global__ __launch_bounds__(128) void u2_kernel(const float* __restrict__ h1,
                                                 const int* __restrict__ i1,
                                                 const float* __restrict__ w1,
                                                 const float* __restrict__ b1,
                                                 float* __restrict__ u2) {
  int row = blockIdx.x;  // 16384
  int f = (int)threadIdx.x;
  int b = row >> 11;
  int src = i1[row];
  const float* x = h1 + ((size_t)b * 4096 + src) * 64;
  float acc = b1[f];
#pragma unroll
  for (int k = 0; k < 64; ++k) acc = fmaf(x[k], w1[k * 128 + f], acc);
  u2[(size_t)row * 128 + f] = acc;
}

__global__ __launch_bounds__(256) void transpose_kernel(const float* __restrict__ w2a,
                                                        const float* __restrict__ w2b,
                                                        float* __restrict__ w2ta,
                                                        float* __restrict__ w2tb) {
  int gtid = blockIdx.x * 256 + (int)threadIdx.x;
  int stride = gridDim.x * 256;
  for (int t = gtid; t < 64 * 64; t += stride) w2ta[(t & 63) * 64 + (t >> 6)] = w2a[t];
  for (int t = gtid; t < 128 * 128; t += stride) w2tb[(t & 127) * 128 + (t >> 7)] = w2b[t];
}

// ---------------- global max pool over i2 + final linear ----------------
__global__ __launch_bounds__(512) void pool_linear_kernel(
    const float* __restrict__ h2, const int* __restrict__ i2,
    const float* __restrict__ wl, const float* __restrict__ bl,
    float* __restrict__ out) {
  int b = blockIdx.x;
  int c = (int)threadIdx.x >> 7;
  int f = (int)threadIdx.x & 127;
  __shared__ float part[4][128];
  __shared__ float feat[128];
  float mx = -__builtin_inff();
  const int* idx = i2 + b * 512;
  for (int s = c * 128; s < c * 128 + 128; ++s) {
    int j = idx[s];
    mx = fmaxf(mx, h2[((size_t)b * 2048 + j) * 128 + f]);
  }
  part[c][f] = mx;
  __syncthreads();
  if (c == 0) {
    feat[f] = fmaxf(fmaxf(part[0][f], part[1][f]), fmaxf(part[2][f], part[3][f]));
  }
  __syncthreads();
  if (c == 0) {
    float acc = bl[f];
#pragma unroll
    for (int k = 0; k < 128; ++k) acc = fmaf(feat[k], wl[k * 128 + f], acc);
    out[b * 128 + f] = acc;
  }
}

extern "C" void kernel_launch(void* const* d_in, const int* in_sizes, int n_in,
                              void* d_out, int out_size, void* d_ws, size_t ws_size,
                              hipStream_t stream) {
  const float* feats = (const float*)d_in[0];   // [8,4096,6]
  const float* coords = (const float*)d_in[1];  // [8,4096,3]
  const float* W1a = (const float*)d_in[2];     // [9,64]
  const float* b1a = (const float*)d_in[3];
  const float* W2a = (const float*)d_in[4];     // [64,64]
  const float* b2a = (const float*)d_in[5];
  const float* W1b = (const float*)d_in[6];     // [67,128]
  const float* b1b = (const float*)d_in[7];
  const float* W2b = (const float*)d_in[8];     // [128,128]
  const float* b2b = (const float*)d_in[9];
  const float* Wl = (const float*)d_in[10];     // [128,128]
  const float* bl = (const float*)d_in[11];

  float* ws = (float*)d_ws;
  float* W2TA = ws;                  // 4096
  float* W2TB = W2TA + 4096;         // 16384
  float* H1 = W2TB + 16384;          // 8*4096*64  = 2097152
  float* U2 = H1 + 2097152;          // 8*2048*128 = 2097152
  float* H2 = U2 + 2097152;          // 8*2048*128 = 2097152
  float* P1 = H2 + 2097152;          // 8*2048*3   = 49152
  int* I1 = (int*)(P1 + 49152);      // 8*2048
  int* I2 = I1 + 16384;              // 8*512

  transpose_kernel<<<80, 256, 0, stream>>>(W2a, W2b, W2TA, W2TB);
  // stage 1: fps1 (blocks 0-7) || conv1 (8192 blocks x 4 queries)
  stage1_kernel<<<8 + 8192, 256, 0, stream>>>(coords, feats, W1a, b1a, W2TA, b2a, H1,
                                              I1, P1);
  u2_kernel<<<16384, 128, 0, stream>>>(H1, I1, W1b, b1b, U2);
  // stage 2: fps2 (blocks 0-7) || conv2 (8192 blocks x 2 queries x 2 waves)
  stage2_kernel<<<8 + 8192, 256, 0, stream>>>(P1, U2, W1b + 64 * 128, W2TB, b2b, H2, I2);
  pool_linear_kernel<<<8, 512, 0, stream>>>(H2, I2, Wl, bl, (float*)d_out);
}